// Round 3
// baseline (948.714 us; speedup 1.0000x reference)
//
#include <hip/hip_runtime.h>

#define NP 30000
#define NA 30000
#define EDG 400000
#define HD 128          // H*D
#define LRELU_ALPHA 0.2f
#define NODE_STRIDE 30016   // padded per-type stride for count/cursor/offset arrays (ints)

// ---------------- GEMM: C[M][128] = A[M][128] @ W[128][128] + b ----------------
// block 256 threads, tile 64 rows x 128 cols, each thread 16 rows x 2 cols.
// fp32 -> no MFMA on CDNA4; vector-FMA bound. W stays L1/L2-resident (64 KB).
__launch_bounds__(256)
__global__ void gemm128(const float* __restrict__ A, const float* __restrict__ W,
                        const float* __restrict__ bias, float* __restrict__ C, int M)
{
    __shared__ float As[64 * 128];
    const int t = threadIdx.x;
    const int row0 = blockIdx.x * 64;
    #pragma unroll
    for (int i = 0; i < 8; ++i) {
        int f4 = t + i * 256;            // 0..2047 float4 slots
        int r = f4 >> 5, c4 = f4 & 31;
        int gr = row0 + r;
        float4 v = make_float4(0.f, 0.f, 0.f, 0.f);
        if (gr < M) v = reinterpret_cast<const float4*>(A)[(size_t)gr * 32 + c4];
        reinterpret_cast<float4*>(As)[f4] = v;
    }
    __syncthreads();
    const int cg = t & 63;   // cols cg and cg+64
    const int rg = t >> 6;   // rows rg*16 .. rg*16+15
    float acc0[16], acc1[16];
    #pragma unroll
    for (int r = 0; r < 16; ++r) { acc0[r] = 0.f; acc1[r] = 0.f; }
    const float* Asr = &As[rg * 16 * 128];
    for (int k = 0; k < 128; k += 4) {
        float w00 = W[(k+0)*128 + cg],    w01 = W[(k+1)*128 + cg],
              w02 = W[(k+2)*128 + cg],    w03 = W[(k+3)*128 + cg];
        float w10 = W[(k+0)*128 + cg+64], w11 = W[(k+1)*128 + cg+64],
              w12 = W[(k+2)*128 + cg+64], w13 = W[(k+3)*128 + cg+64];
        #pragma unroll
        for (int r = 0; r < 16; ++r) {
            // all 64 lanes of a wave read the SAME As address -> LDS broadcast, no conflict
            float4 f = *reinterpret_cast<const float4*>(&Asr[r * 128 + k]);
            acc0[r] += f.x*w00 + f.y*w01 + f.z*w02 + f.w*w03;
            acc1[r] += f.x*w10 + f.y*w11 + f.z*w12 + f.w*w13;
        }
    }
    float b0 = bias[cg], b1 = bias[cg + 64];
    #pragma unroll
    for (int r = 0; r < 16; ++r) {
        int gr = row0 + rg * 16 + r;
        if (gr < M) {
            C[(size_t)gr * 128 + cg]      = acc0[r] + b0;
            C[(size_t)gr * 128 + cg + 64] = acc1[r] + b1;
        }
    }
}

// ---------------- state linear: out[128] = feat[K] @ W[K][128] + b ----------------
__global__ void state_lin(const float* __restrict__ feat, const float* __restrict__ W,
                          const float* __restrict__ b, float* __restrict__ out, int K)
{
    int n = threadIdx.x;   // 128 threads
    float acc = b[n];
    for (int k = 0; k < K; ++k) acc += feat[k] * W[k * 128 + n];
    out[n] = acc;
}

// ------- rowdot: o[i][h] = sum_d Wh[i][h*32+d]*a[h*32+d] (up to two attn vecs) -------
__launch_bounds__(256)
__global__ void rowdot2(const float* __restrict__ Wh,
                        const float* __restrict__ a1, float* __restrict__ o1,
                        const float* __restrict__ a2, float* __restrict__ o2, int n)
{
    int lane = threadIdx.x & 31;
    int node = (blockIdx.x * blockDim.x + threadIdx.x) >> 5;
    if (node >= n) return;
    const float* row = Wh + (size_t)node * 128;
    float s1[4], s2[4];
    #pragma unroll
    for (int h = 0; h < 4; ++h) {
        float v = row[h * 32 + lane];
        s1[h] = v * a1[h * 32 + lane];
        s2[h] = o2 ? v * a2[h * 32 + lane] : 0.f;
    }
    #pragma unroll
    for (int off = 16; off; off >>= 1) {
        #pragma unroll
        for (int h = 0; h < 4; ++h) {
            s1[h] += __shfl_xor(s1[h], off, 32);
            s2[h] += __shfl_xor(s2[h], off, 32);
        }
    }
    if (lane == 0) {
        #pragma unroll
        for (int h = 0; h < 4; ++h) o1[node * 4 + h] = s1[h];
        if (o2) {
            #pragma unroll
            for (int h = 0; h < 4; ++h) o2[node * 4 + h] = s2[h];
        }
    }
}

// ---------------- CSR build step 1: histogram of dst ----------------
__launch_bounds__(256)
__global__ void hist_dst(const int* __restrict__ dst, int* __restrict__ cnt, int nE)
{
    int e = blockIdx.x * 256 + threadIdx.x;
    if (e < nE) atomicAdd(&cnt[dst[e]], 1);
}

// ---------------- CSR build step 2: scan counts -> offsets + cursor ----------------
// grid = 4 blocks (one per edge type), block = 1024 threads (16 waves of 64).
__launch_bounds__(1024)
__global__ void scan4(const int* __restrict__ counts, int* __restrict__ offsets,
                      int* __restrict__ cursor, int n)
{
    const int* cnt = counts + blockIdx.x * NODE_STRIDE;
    int* off = offsets + blockIdx.x * NODE_STRIDE;
    int* cur = cursor + blockIdx.x * NODE_STRIDE;
    int t = threadIdx.x;
    int lane = t & 63, wv = t >> 6;
    __shared__ int wsum[16];
    __shared__ int carry_s;
    if (t == 0) { carry_s = 0; off[0] = 0; }
    __syncthreads();
    for (int base = 0; base < n; base += 1024) {
        int i = base + t;
        int v = (i < n) ? cnt[i] : 0;
        int x = v;                           // inclusive scan within wave
        #pragma unroll
        for (int o = 1; o < 64; o <<= 1) {
            int y = __shfl_up(x, o, 64);
            if (lane >= o) x += y;
        }
        if (lane == 63) wsum[wv] = x;
        __syncthreads();
        if (wv == 0) {                       // scan the 16 wave sums
            int y = (lane < 16) ? wsum[lane] : 0;
            #pragma unroll
            for (int o = 1; o < 16; o <<= 1) {
                int z = __shfl_up(y, o, 64);
                if (lane >= o) y += z;
            }
            if (lane < 16) wsum[lane] = y;
        }
        __syncthreads();
        int add = carry_s + (wv > 0 ? wsum[wv - 1] : 0);
        int incl = x + add;
        if (i < n) { off[i + 1] = incl; cur[i] = incl - v; }
        __syncthreads();
        if (t == 0) carry_s += wsum[15];
        __syncthreads();
    }
}

// ---- CSR build step 3: scatter edges by dst; compute w = exp(leaky(es+ed)) inline ----
__launch_bounds__(256)
__global__ void scatter_edges(const int* __restrict__ src, const int* __restrict__ dst,
                              const float* __restrict__ es, const float* __restrict__ ed,
                              int* __restrict__ cursor, int* __restrict__ srcs,
                              float* __restrict__ w4, int nE)
{
    int e = blockIdx.x * 256 + threadIdx.x;
    if (e >= nE) return;
    int s = src[e], d = dst[e];
    float4 a = *reinterpret_cast<const float4*>(&es[s * 4]);
    float4 b = *reinterpret_cast<const float4*>(&ed[d * 4]);
    float x0 = a.x + b.x, x1 = a.y + b.y, x2 = a.z + b.z, x3 = a.w + b.w;
    x0 = x0 > 0.f ? x0 : LRELU_ALPHA * x0;
    x1 = x1 > 0.f ? x1 : LRELU_ALPHA * x1;
    x2 = x2 > 0.f ? x2 : LRELU_ALPHA * x2;
    x3 = x3 > 0.f ? x3 : LRELU_ALPHA * x3;
    // softmax is shift-invariant; e = es+ed is O(1) (inputs ~N(0,sigma<1)), so skipping
    // the segment-max subtraction is exact in math and overflow-safe in fp32.
    float4 w = make_float4(__expf(x0), __expf(x1), __expf(x2), __expf(x3));
    int pos = atomicAdd(&cursor[d], 1);
    srcs[pos] = s;
    reinterpret_cast<float4*>(w4)[pos] = w;
}

// ---- aggregate one edge type (no atomics), normalize, ADD into out ----
// one 64-lane wave per dst node; lane owns features lane and lane+64.
__launch_bounds__(256)
__global__ void aggregate_add(const float* __restrict__ Wh,
                              const int* __restrict__ off, const int* __restrict__ srcs,
                              const float* __restrict__ w4,
                              float* __restrict__ out, int n)
{
    int lane = threadIdx.x & 63;
    int node = (blockIdx.x * blockDim.x + threadIdx.x) >> 6;
    if (node >= n) return;
    const int h0 = lane >> 5;            // head of feature f0=lane; f1=lane+64 -> head h0+2
    float accA = 0.f, accB = 0.f, dA = 0.f, dB = 0.f;
    int b = off[node], e = off[node + 1];
    for (int i = b; i < e; ++i) {
        int s = srcs[i];                 // broadcast scalar load
        float wA = w4[i * 4 + h0];
        float wB = w4[i * 4 + h0 + 2];
        const float* row = Wh + (size_t)s * 128;
        accA += wA * row[lane];
        accB += wB * row[lane + 64];
        dA += wA; dB += wB;
    }
    float iA = dA > 0.f ? 1.f / dA : 0.f;
    float iB = dB > 0.f ? 1.f / dB : 0.f;
    float* o = out + (size_t)node * 128;
    o[lane]      += accA * iA;
    o[lane + 64] += accB * iB;
}

// ---- elementwise relu over out ----
__launch_bounds__(256)
__global__ void relu_pass(float* __restrict__ out, int n4)
{
    int idx = blockIdx.x * 256 + threadIdx.x;
    int stride = gridDim.x * 256;
    for (int i = idx; i < n4; i += stride) {
        float4 v = reinterpret_cast<float4*>(out)[i];
        v.x = v.x > 0.f ? v.x : 0.f;
        v.y = v.y > 0.f ? v.y : 0.f;
        v.z = v.z > 0.f ? v.z : 0.f;
        v.w = v.w > 0.f ? v.w : 0.f;
        reinterpret_cast<float4*>(out)[i] = v;
    }
}

// ------- state reduce (p2s/a2s): SS[hd] += w_i*WhT[src_i][hd], dS[h] += w_i -------
__launch_bounds__(256)
__global__ void state_reduce(const float* __restrict__ WhT, const int* __restrict__ srcArr,
                             const float* __restrict__ attn_src, const float* __restrict__ attn_dst,
                             const float* __restrict__ Wh_in, float* __restrict__ SS,
                             float* __restrict__ dS, int n)
{
    int lane = threadIdx.x & 31;
    int sub = threadIdx.x >> 5;   // 0..7
    float as[4], eds[4];
    #pragma unroll
    for (int h = 0; h < 4; ++h) {
        as[h]  = attn_src[h * 32 + lane];
        eds[h] = Wh_in[h * 32 + lane] * attn_dst[h * 32 + lane];
    }
    #pragma unroll
    for (int off = 16; off; off >>= 1) {
        #pragma unroll
        for (int h = 0; h < 4; ++h) eds[h] += __shfl_xor(eds[h], off, 32);
    }
    float acc[4] = {0.f, 0.f, 0.f, 0.f};
    float dacc[4] = {0.f, 0.f, 0.f, 0.f};
    int stride = gridDim.x * 8;
    for (int i = blockIdx.x * 8 + sub; i < n; i += stride) {
        int s = srcArr[i];
        float v[4], p[4];
        #pragma unroll
        for (int h = 0; h < 4; ++h) { v[h] = WhT[(size_t)s * 128 + h * 32 + lane]; p[h] = v[h] * as[h]; }
        #pragma unroll
        for (int off = 16; off; off >>= 1) {
            #pragma unroll
            for (int h = 0; h < 4; ++h) p[h] += __shfl_xor(p[h], off, 32);
        }
        #pragma unroll
        for (int h = 0; h < 4; ++h) {
            float x = p[h] + eds[h];
            x = x > 0.f ? x : LRELU_ALPHA * x;
            float w = __expf(x);
            acc[h] += w * v[h];
            dacc[h] += w;
        }
    }
    __shared__ float red[8][128];
    __shared__ float dred[8][4];
    #pragma unroll
    for (int h = 0; h < 4; ++h) red[sub][h * 32 + lane] = acc[h];
    if (lane == 0) {
        #pragma unroll
        for (int h = 0; h < 4; ++h) dred[sub][h] = dacc[h];
    }
    __syncthreads();
    int t = threadIdx.x;
    if (t < 128) {
        float s = 0.f;
        #pragma unroll
        for (int j = 0; j < 8; ++j) s += red[j][t];
        atomicAdd(&SS[t], s);
    }
    if (t < 4) {
        float s = 0.f;
        #pragma unroll
        for (int j = 0; j < 8; ++j) s += dred[j][t];
        atomicAdd(&dS[t], s);
    }
}

__global__ void finalize_state(const float* __restrict__ Wh_in, const float* __restrict__ SS0,
                               const float* __restrict__ dS0, const float* __restrict__ SS1,
                               const float* __restrict__ dS1, float* __restrict__ out)
{
    int t = threadIdx.x;   // 128
    int h = t >> 5;
    float v0 = dS0[h]; float i0 = v0 > 0.f ? 1.f / v0 : 0.f;
    float v1 = dS1[h]; float i1 = v1 > 0.f ? 1.f / v1 : 0.f;
    float v = Wh_in[t] + SS0[t] * i0 + SS1[t] * i1;
    out[t] = v > 0.f ? v : 0.f;
}

extern "C" void kernel_launch(void* const* d_in, const int* in_sizes, int n_in,
                              void* d_out, int out_size, void* d_ws, size_t ws_size,
                              hipStream_t stream)
{
    const float* feat_P = (const float*)d_in[0];
    const float* feat_A = (const float*)d_in[1];
    const float* feat_state = (const float*)d_in[2];
    const float* W_P   = (const float*)d_in[3];  const float* b_P   = (const float*)d_in[4];
    const float* W_A   = (const float*)d_in[5];  const float* b_A   = (const float*)d_in[6];
    const float* W_p2p = (const float*)d_in[7];  const float* b_p2p = (const float*)d_in[8];
    const float* W_p2a = (const float*)d_in[9];  const float* b_p2a = (const float*)d_in[10];
    const float* W_a2p = (const float*)d_in[11]; const float* b_a2p = (const float*)d_in[12];
    const float* W_a2a = (const float*)d_in[13]; const float* b_a2a = (const float*)d_in[14];
    const float* W_p2s = (const float*)d_in[15]; const float* b_p2s = (const float*)d_in[16];
    const float* W_a2s = (const float*)d_in[17]; const float* b_a2s = (const float*)d_in[18];
    const float* W_in  = (const float*)d_in[19]; const float* b_in  = (const float*)d_in[20];
    const float* at_p2p_s = (const float*)d_in[21]; const float* at_p2p_d = (const float*)d_in[22];
    const float* at_p2a_s = (const float*)d_in[23]; const float* at_p2a_d = (const float*)d_in[24];
    const float* at_a2p_s = (const float*)d_in[25]; const float* at_a2p_d = (const float*)d_in[26];
    const float* at_a2a_s = (const float*)d_in[27]; const float* at_a2a_d = (const float*)d_in[28];
    const float* at_p2s_s = (const float*)d_in[29]; const float* at_p2s_d = (const float*)d_in[30];
    const float* at_a2s_s = (const float*)d_in[31]; const float* at_a2s_d = (const float*)d_in[32];
    const int* src_p2p = (const int*)d_in[33]; const int* dst_p2p = (const int*)d_in[34];
    const int* src_p2a = (const int*)d_in[35]; const int* dst_p2a = (const int*)d_in[36];
    const int* src_a2p = (const int*)d_in[37]; const int* dst_a2p = (const int*)d_in[38];
    const int* src_a2a = (const int*)d_in[39]; const int* dst_a2a = (const int*)d_in[40];
    const int* src_p2s = (const int*)d_in[41];
    const int* src_a2s = (const int*)d_in[43];
    float* out = (float*)d_out;

    // ---------------- workspace layout (all chunks 16B-multiple) ----------------
    char* base = (char*)d_ws;
    float* WhT    = (float*)base;  base += (size_t)NP * HD * 4;   // 15.36 MB (one edge-type table at a time)
    float* w4     = (float*)base;  base += (size_t)EDG * 4 * 4;   // 6.4 MB
    int*   srcs   = (int*)base;    base += (size_t)EDG * 4;       // 1.6 MB
    float* ed_p2p = (float*)base;  base += NP * 4 * 4;
    float* ed_a2p = (float*)base;  base += NP * 4 * 4;
    float* ed_p2a = (float*)base;  base += NA * 4 * 4;
    float* ed_a2a = (float*)base;  base += NA * 4 * 4;
    float* es     = (float*)base;  base += NP * 4 * 4;
    int*   counts = (int*)base;    base += 4 * NODE_STRIDE * 4;   // 4 edge types
    int*   cursor = (int*)base;    base += 4 * NODE_STRIDE * 4;
    int*   offs   = (int*)base;    base += 4 * NODE_STRIDE * 4;
    float* Wh_inb = (float*)base;  base += 128 * 4;
    float* SS0    = (float*)base;  base += 128 * 4;
    float* SS1    = (float*)base;  base += 128 * 4;
    float* dS0    = (float*)base;  base += 4 * 4;
    float* dS1    = (float*)base;  base += 16;                    // keep end 16B-aligned
    size_t needed = (size_t)(base - (char*)d_ws);
    if (ws_size < needed) return;   // diagnostic guard: fail validation, not the container

    int* cnt_p2p = counts;                 int* cur_p2p = cursor;                 int* off_p2p = offs;
    int* cnt_a2p = counts + NODE_STRIDE;   int* cur_a2p = cursor + NODE_STRIDE;   int* off_a2p = offs + NODE_STRIDE;
    int* cnt_p2a = counts + 2*NODE_STRIDE; int* cur_p2a = cursor + 2*NODE_STRIDE; int* off_p2a = offs + 2*NODE_STRIDE;
    int* cnt_a2a = counts + 3*NODE_STRIDE; int* cur_a2a = cursor + 3*NODE_STRIDE; int* off_a2a = offs + 3*NODE_STRIDE;

    float* outP = out;
    float* outA = out + (size_t)NP * HD;
    float* outS = out + (size_t)(NP + NA) * HD;

    const dim3 B(256);
    const int gGemm = (NP + 63) / 64;
    const int gNodeW32 = (NP * 32 + 255) / 256;  // rowdot grids (32 lanes/node)
    const int gNodeW64 = (NP * 64 + 255) / 256;  // aggregate grids (64 lanes/node)
    const int gEdgeT = (EDG + 255) / 256;
    const int gRelu = 2048;

    // ---- CSR builds (depend only on dst index arrays) ----
    hipMemsetAsync(counts, 0, 4 * NODE_STRIDE * sizeof(int), stream);
    hist_dst<<<gEdgeT, B, 0, stream>>>(dst_p2p, cnt_p2p, EDG);
    hist_dst<<<gEdgeT, B, 0, stream>>>(dst_a2p, cnt_a2p, EDG);
    hist_dst<<<gEdgeT, B, 0, stream>>>(dst_p2a, cnt_p2a, EDG);
    hist_dst<<<gEdgeT, B, 0, stream>>>(dst_a2a, cnt_a2a, EDG);
    scan4<<<4, 1024, 0, stream>>>(counts, offs, cursor, NP);

    state_lin<<<1, 128, 0, stream>>>(feat_state, W_in, b_in, Wh_inb, 64);

    // ================= phase P (Wh_P lives directly in outP) =================
    gemm128<<<gGemm, B, 0, stream>>>(feat_P, W_P, b_P, outP, NP);
    rowdot2<<<gNodeW32, B, 0, stream>>>(outP, at_p2p_d, ed_p2p, at_a2p_d, ed_a2p, NP);
    // p2p
    gemm128<<<gGemm, B, 0, stream>>>(feat_P, W_p2p, b_p2p, WhT, NP);
    rowdot2<<<gNodeW32, B, 0, stream>>>(WhT, at_p2p_s, es, nullptr, nullptr, NP);
    scatter_edges<<<gEdgeT, B, 0, stream>>>(src_p2p, dst_p2p, es, ed_p2p, cur_p2p, srcs, w4, EDG);
    aggregate_add<<<gNodeW64, B, 0, stream>>>(WhT, off_p2p, srcs, w4, outP, NP);
    // a2p
    gemm128<<<gGemm, B, 0, stream>>>(feat_A, W_a2p, b_a2p, WhT, NA);
    rowdot2<<<gNodeW32, B, 0, stream>>>(WhT, at_a2p_s, es, nullptr, nullptr, NA);
    scatter_edges<<<gEdgeT, B, 0, stream>>>(src_a2p, dst_a2p, es, ed_a2p, cur_a2p, srcs, w4, EDG);
    aggregate_add<<<gNodeW64, B, 0, stream>>>(WhT, off_a2p, srcs, w4, outP, NP);
    relu_pass<<<gRelu, B, 0, stream>>>(outP, NP * 32);

    // ================= phase A (Wh_A lives directly in outA) =================
    gemm128<<<gGemm, B, 0, stream>>>(feat_A, W_A, b_A, outA, NA);
    rowdot2<<<gNodeW32, B, 0, stream>>>(outA, at_p2a_d, ed_p2a, at_a2a_d, ed_a2a, NA);
    // p2a
    gemm128<<<gGemm, B, 0, stream>>>(feat_P, W_p2a, b_p2a, WhT, NP);
    rowdot2<<<gNodeW32, B, 0, stream>>>(WhT, at_p2a_s, es, nullptr, nullptr, NP);
    scatter_edges<<<gEdgeT, B, 0, stream>>>(src_p2a, dst_p2a, es, ed_p2a, cur_p2a, srcs, w4, EDG);
    aggregate_add<<<gNodeW64, B, 0, stream>>>(WhT, off_p2a, srcs, w4, outA, NA);
    // a2a
    gemm128<<<gGemm, B, 0, stream>>>(feat_A, W_a2a, b_a2a, WhT, NA);
    rowdot2<<<gNodeW32, B, 0, stream>>>(WhT, at_a2a_s, es, nullptr, nullptr, NA);
    scatter_edges<<<gEdgeT, B, 0, stream>>>(src_a2a, dst_a2a, es, ed_a2a, cur_a2a, srcs, w4, EDG);
    aggregate_add<<<gNodeW64, B, 0, stream>>>(WhT, off_a2a, srcs, w4, outA, NA);
    relu_pass<<<gRelu, B, 0, stream>>>(outA, NA * 32);

    // ================= state (p2s / a2s; all edges -> single node 0) =================
    hipMemsetAsync(SS0, 0, (128 + 128 + 4 + 4) * sizeof(float), stream);  // SS0,SS1,dS0,dS1 contiguous
    gemm128<<<gGemm, B, 0, stream>>>(feat_P, W_p2s, b_p2s, WhT, NP);
    state_reduce<<<512, B, 0, stream>>>(WhT, src_p2s, at_p2s_s, at_p2s_d, Wh_inb, SS0, dS0, NP);
    gemm128<<<gGemm, B, 0, stream>>>(feat_A, W_a2s, b_a2s, WhT, NA);
    state_reduce<<<512, B, 0, stream>>>(WhT, src_a2s, at_a2s_s, at_a2s_d, Wh_inb, SS1, dS1, NA);
    finalize_state<<<1, 128, 0, stream>>>(Wh_inb, SS0, dS0, SS1, dS1, outS);
}

// Round 6
// 796.948 us; speedup vs baseline: 1.1904x; 1.1904x over previous
//
#include <hip/hip_runtime.h>

#define NP 30000
#define NA 30000
#define EDG 400000
#define HD 128          // H*D
#define LRELU_ALPHA 0.2f
#define NODE_STRIDE 30016   // padded per-type stride for count/cursor/offset arrays (ints)

__device__ __forceinline__ float lrelu(float x) { return x > 0.f ? x : LRELU_ALPHA * x; }

// ---------------- GEMM + fused rowdot epilogue ----------------
// C[M][128] = A[M][128] @ W[128][128] + b ; block 256 = 4 waves, tile 64x128,
// thread: 16 rows x 2 cols (cg, cg+64). Wave rg owns rows rg*16..+15 ENTIRELY
// -> per-row head-dots via 32-wide shuffle butterflies on in-register accs.
// NRD = number of attention vectors to dot (0, 1, or 2). o*[node*4+h].
template<int NRD>
__launch_bounds__(256)
__global__ void gemm_rd(const float* __restrict__ A, const float* __restrict__ W,
                        const float* __restrict__ bias, float* __restrict__ C, int M,
                        const float* __restrict__ a1, float* __restrict__ o1,
                        const float* __restrict__ a2, float* __restrict__ o2)
{
    __shared__ float As[64 * 128];
    const int t = threadIdx.x;
    const int row0 = blockIdx.x * 64;
    #pragma unroll
    for (int i = 0; i < 8; ++i) {
        int f4 = t + i * 256;            // 0..2047 float4 slots
        int r = f4 >> 5, c4 = f4 & 31;
        int gr = row0 + r;
        float4 v = make_float4(0.f, 0.f, 0.f, 0.f);
        if (gr < M) v = reinterpret_cast<const float4*>(A)[(size_t)gr * 32 + c4];
        reinterpret_cast<float4*>(As)[f4] = v;
    }
    __syncthreads();
    const int cg = t & 63;   // cols cg and cg+64
    const int rg = t >> 6;   // wave id; rows rg*16 .. rg*16+15
    float acc0[16], acc1[16];
    #pragma unroll
    for (int r = 0; r < 16; ++r) { acc0[r] = 0.f; acc1[r] = 0.f; }
    const float* Asr = &As[rg * 16 * 128];
    for (int k = 0; k < 128; k += 4) {
        float w00 = W[(k+0)*128 + cg],    w01 = W[(k+1)*128 + cg],
              w02 = W[(k+2)*128 + cg],    w03 = W[(k+3)*128 + cg];
        float w10 = W[(k+0)*128 + cg+64], w11 = W[(k+1)*128 + cg+64],
              w12 = W[(k+2)*128 + cg+64], w13 = W[(k+3)*128 + cg+64];
        #pragma unroll
        for (int r = 0; r < 16; ++r) {
            float4 f = *reinterpret_cast<const float4*>(&Asr[r * 128 + k]);
            acc0[r] += f.x*w00 + f.y*w01 + f.z*w02 + f.w*w03;
            acc1[r] += f.x*w10 + f.y*w11 + f.z*w12 + f.w*w13;
        }
    }
    float b0 = bias[cg], b1 = bias[cg + 64];
    #pragma unroll
    for (int r = 0; r < 16; ++r) { acc0[r] += b0; acc1[r] += b1; }
    // store C
    #pragma unroll
    for (int r = 0; r < 16; ++r) {
        int gr = row0 + rg * 16 + r;
        if (gr < M) {
            C[(size_t)gr * 128 + cg]      = acc0[r];
            C[(size_t)gr * 128 + cg + 64] = acc1[r];
        }
    }
    if (NRD >= 1) {
        float a10 = a1[cg], a11 = a1[cg + 64];
        float a20 = 0.f, a21 = 0.f;
        if (NRD == 2) { a20 = a2[cg]; a21 = a2[cg + 64]; }
        #pragma unroll
        for (int r = 0; r < 16; ++r) {
            int node = row0 + rg * 16 + r;
            if (node >= M) break;      // wave-uniform
            float t10 = acc0[r] * a10, t11 = acc1[r] * a11;   // heads (cg>>5), (cg>>5)+2
            float t20 = 0.f, t21 = 0.f;
            if (NRD == 2) { t20 = acc0[r] * a20; t21 = acc1[r] * a21; }
            #pragma unroll
            for (int off = 16; off; off >>= 1) {
                t10 += __shfl_xor(t10, off, 32);
                t11 += __shfl_xor(t11, off, 32);
                if (NRD == 2) { t20 += __shfl_xor(t20, off, 32); t21 += __shfl_xor(t21, off, 32); }
            }
            // lanes 0..31 now all hold head0 (t10) / head2 (t11); lanes 32..63 head1/head3
            if (cg == 0)  { o1[node*4+0] = t10; o1[node*4+2] = t11;
                            if (NRD == 2) { o2[node*4+0] = t20; o2[node*4+2] = t21; } }
            if (cg == 32) { o1[node*4+1] = t10; o1[node*4+3] = t11;
                            if (NRD == 2) { o2[node*4+1] = t20; o2[node*4+3] = t21; } }
        }
    }
}

// ---------------- GEMM fused with state-edge aggregation (p2s/a2s) ----------------
// Never writes Wh: per row computes s_h = dot(row, as), w = exp(lrelu(s_h + eds_h)),
// accumulates w*row (per-column) and w (per-head), block-reduces, atomics to SS/dS.
__launch_bounds__(256)
__global__ void gemm_state(const float* __restrict__ A, const float* __restrict__ W,
                           const float* __restrict__ bias, int M,
                           const float* __restrict__ as_vec, const float* __restrict__ eds,
                           float* __restrict__ SS, float* __restrict__ dS)
{
    __shared__ float As[64 * 128];
    const int t = threadIdx.x;
    const int row0 = blockIdx.x * 64;
    #pragma unroll
    for (int i = 0; i < 8; ++i) {
        int f4 = t + i * 256;
        int r = f4 >> 5, c4 = f4 & 31;
        int gr = row0 + r;
        float4 v = make_float4(0.f, 0.f, 0.f, 0.f);
        if (gr < M) v = reinterpret_cast<const float4*>(A)[(size_t)gr * 32 + c4];
        reinterpret_cast<float4*>(As)[f4] = v;
    }
    __syncthreads();
    const int cg = t & 63;
    const int rg = t >> 6;
    float acc0[16], acc1[16];
    #pragma unroll
    for (int r = 0; r < 16; ++r) { acc0[r] = 0.f; acc1[r] = 0.f; }
    const float* Asr = &As[rg * 16 * 128];
    for (int k = 0; k < 128; k += 4) {
        float w00 = W[(k+0)*128 + cg],    w01 = W[(k+1)*128 + cg],
              w02 = W[(k+2)*128 + cg],    w03 = W[(k+3)*128 + cg];
        float w10 = W[(k+0)*128 + cg+64], w11 = W[(k+1)*128 + cg+64],
              w12 = W[(k+2)*128 + cg+64], w13 = W[(k+3)*128 + cg+64];
        #pragma unroll
        for (int r = 0; r < 16; ++r) {
            float4 f = *reinterpret_cast<const float4*>(&Asr[r * 128 + k]);
            acc0[r] += f.x*w00 + f.y*w01 + f.z*w02 + f.w*w03;
            acc1[r] += f.x*w10 + f.y*w11 + f.z*w12 + f.w*w13;
        }
    }
    float b0 = bias[cg], b1 = bias[cg + 64];
    float av0 = as_vec[cg], av1 = as_vec[cg + 64];
    float e0 = eds[cg >> 5];        // head of col cg (0 or 1)
    float e1 = eds[2 + (cg >> 5)];  // head of col cg+64 (2 or 3)
    float sacc0 = 0.f, sacc1 = 0.f, ds0 = 0.f, ds1 = 0.f;
    #pragma unroll
    for (int r = 0; r < 16; ++r) {
        int node = row0 + rg * 16 + r;
        if (node >= M) break;       // wave-uniform
        float f0 = acc0[r] + b0, f1 = acc1[r] + b1;
        float t0 = f0 * av0, t1 = f1 * av1;
        #pragma unroll
        for (int off = 16; off; off >>= 1) {
            t0 += __shfl_xor(t0, off, 32);
            t1 += __shfl_xor(t1, off, 32);
        }
        float w0 = __expf(lrelu(t0 + e0));   // all 32 lanes of the group share w
        float w1 = __expf(lrelu(t1 + e1));
        sacc0 += w0 * f0; sacc1 += w1 * f1;
        ds0 += w0; ds1 += w1;
    }
    __shared__ float red[4][128];
    __shared__ float dred[4][4];
    red[rg][cg] = sacc0;
    red[rg][cg + 64] = sacc1;
    if (cg == 0)  { dred[rg][0] = ds0; dred[rg][2] = ds1; }
    if (cg == 32) { dred[rg][1] = ds0; dred[rg][3] = ds1; }
    __syncthreads();
    if (t < 128) {
        float s = red[0][t] + red[1][t] + red[2][t] + red[3][t];
        atomicAdd(&SS[t], s);
    }
    if (t < 4) {
        float s = dred[0][t] + dred[1][t] + dred[2][t] + dred[3][t];
        atomicAdd(&dS[t], s);
    }
}

// ---------------- state linear: out[128] = feat[K] @ W[K][128] + b ----------------
__global__ void state_lin(const float* __restrict__ feat, const float* __restrict__ W,
                          const float* __restrict__ b, float* __restrict__ out, int K)
{
    int n = threadIdx.x;   // 128 threads
    float acc = b[n];
    for (int k = 0; k < K; ++k) acc += feat[k] * W[k * 128 + n];
    out[n] = acc;
}

// ---- tiny: per-head dots of Wh_in with the two state dst-attn vectors ----
__global__ void edot2(const float* __restrict__ Wh_inb, const float* __restrict__ aP,
                      const float* __restrict__ aA, float* __restrict__ edsP,
                      float* __restrict__ edsA)
{
    int t = threadIdx.x;   // 128
    int l = t & 31;
    float v = Wh_inb[t];
    float p = v * aP[t];
    float q = v * aA[t];
    #pragma unroll
    for (int off = 16; off; off >>= 1) {
        p += __shfl_xor(p, off, 32);
        q += __shfl_xor(q, off, 32);
    }
    if (l == 0) { edsP[t >> 5] = p; edsA[t >> 5] = q; }
}

// ---------------- CSR build step 1: histogram of dst ----------------
__launch_bounds__(256)
__global__ void hist_dst(const int* __restrict__ dst, int* __restrict__ cnt, int nE)
{
    int e = blockIdx.x * 256 + threadIdx.x;
    if (e < nE) atomicAdd(&cnt[dst[e]], 1);
}

// ---------------- CSR build step 2: scan counts -> offsets + cursor ----------------
// grid = 4 blocks (one per edge type), block = 1024 threads (16 waves of 64).
__launch_bounds__(1024)
__global__ void scan4(const int* __restrict__ counts, int* __restrict__ offsets,
                      int* __restrict__ cursor, int n)
{
    const int* cnt = counts + blockIdx.x * NODE_STRIDE;
    int* off = offsets + blockIdx.x * NODE_STRIDE;
    int* cur = cursor + blockIdx.x * NODE_STRIDE;
    int t = threadIdx.x;
    int lane = t & 63, wv = t >> 6;
    __shared__ int wsum[16];
    __shared__ int carry_s;
    if (t == 0) { carry_s = 0; off[0] = 0; }
    __syncthreads();
    for (int base = 0; base < n; base += 1024) {
        int i = base + t;
        int v = (i < n) ? cnt[i] : 0;
        int x = v;
        #pragma unroll
        for (int o = 1; o < 64; o <<= 1) {
            int y = __shfl_up(x, o, 64);
            if (lane >= o) x += y;
        }
        if (lane == 63) wsum[wv] = x;
        __syncthreads();
        if (wv == 0) {
            int y = (lane < 16) ? wsum[lane] : 0;
            #pragma unroll
            for (int o = 1; o < 16; o <<= 1) {
                int z = __shfl_up(y, o, 64);
                if (lane >= o) y += z;
            }
            if (lane < 16) wsum[lane] = y;
        }
        __syncthreads();
        int add = carry_s + (wv > 0 ? wsum[wv - 1] : 0);
        int incl = x + add;
        if (i < n) { off[i + 1] = incl; cur[i] = incl - v; }
        __syncthreads();
        if (t == 0) carry_s += wsum[15];
        __syncthreads();
    }
}

// ---- CSR build step 3: scatter edges by dst; w = exp(lrelu(es+ed)) inline ----
__launch_bounds__(256)
__global__ void scatter_edges(const int* __restrict__ src, const int* __restrict__ dst,
                              const float* __restrict__ es, const float* __restrict__ ed,
                              int* __restrict__ cursor, int* __restrict__ srcs,
                              float* __restrict__ w4, int nE)
{
    int e = blockIdx.x * 256 + threadIdx.x;
    if (e >= nE) return;
    int s = src[e], d = dst[e];
    float4 a = *reinterpret_cast<const float4*>(&es[s * 4]);
    float4 b = *reinterpret_cast<const float4*>(&ed[d * 4]);
    // softmax is shift-invariant; scores are O(1) (inputs ~N(0,sigma<1)), so skipping
    // the segment-max subtraction is exact in math and overflow-safe in fp32.
    float4 w = make_float4(__expf(lrelu(a.x + b.x)), __expf(lrelu(a.y + b.y)),
                           __expf(lrelu(a.z + b.z)), __expf(lrelu(a.w + b.w)));
    int pos = atomicAdd(&cursor[d], 1);
    srcs[pos] = s;
    reinterpret_cast<float4*>(w4)[pos] = w;
}

// ---- aggregate one edge type (no atomics), normalize, ADD into out ----
// one 64-lane wave per dst node; lane owns the float2 at features 2*lane..2*lane+1
// (single head per lane -> ONE weight load per edge), 4-edge unroll for MLP.
template<int DO_RELU>
__launch_bounds__(256)
__global__ void aggregate_add(const float* __restrict__ Wh,
                              const int* __restrict__ off, const int* __restrict__ srcs,
                              const float* __restrict__ w4,
                              float* __restrict__ out, int n)
{
    int lane = threadIdx.x & 63;
    int node = (blockIdx.x * blockDim.x + threadIdx.x) >> 6;
    if (node >= n) return;
    const int h = lane >> 4;             // head of features 2*lane, 2*lane+1
    float acc0 = 0.f, acc1 = 0.f, d = 0.f;
    int b = off[node], e = off[node + 1];
    int i = b;
    for (; i + 4 <= e; i += 4) {
        int s0 = srcs[i], s1 = srcs[i+1], s2 = srcs[i+2], s3 = srcs[i+3];
        float w0 = w4[(i+0)*4 + h], w1 = w4[(i+1)*4 + h],
              w2 = w4[(i+2)*4 + h], w3 = w4[(i+3)*4 + h];
        float2 x0 = *reinterpret_cast<const float2*>(&Wh[(size_t)s0*128 + lane*2]);
        float2 x1 = *reinterpret_cast<const float2*>(&Wh[(size_t)s1*128 + lane*2]);
        float2 x2 = *reinterpret_cast<const float2*>(&Wh[(size_t)s2*128 + lane*2]);
        float2 x3 = *reinterpret_cast<const float2*>(&Wh[(size_t)s3*128 + lane*2]);
        acc0 += w0*x0.x + w1*x1.x + w2*x2.x + w3*x3.x;
        acc1 += w0*x0.y + w1*x1.y + w2*x2.y + w3*x3.y;
        d += w0 + w1 + w2 + w3;
    }
    for (; i < e; ++i) {
        int s = srcs[i];
        float w = w4[i*4 + h];
        float2 x = *reinterpret_cast<const float2*>(&Wh[(size_t)s*128 + lane*2]);
        acc0 += w * x.x; acc1 += w * x.y; d += w;
    }
    float inv = d > 0.f ? 1.f / d : 0.f;
    float2* op = reinterpret_cast<float2*>(out + (size_t)node * 128) + lane;
    float2 o = *op;
    o.x += acc0 * inv;
    o.y += acc1 * inv;
    if (DO_RELU) { o.x = o.x > 0.f ? o.x : 0.f; o.y = o.y > 0.f ? o.y : 0.f; }
    *op = o;
}

__global__ void finalize_state(const float* __restrict__ Wh_in, const float* __restrict__ SS0,
                               const float* __restrict__ dS0, const float* __restrict__ SS1,
                               const float* __restrict__ dS1, float* __restrict__ out)
{
    int t = threadIdx.x;   // 128
    int h = t >> 5;
    float v0 = dS0[h]; float i0 = v0 > 0.f ? 1.f / v0 : 0.f;
    float v1 = dS1[h]; float i1 = v1 > 0.f ? 1.f / v1 : 0.f;
    float v = Wh_in[t] + SS0[t] * i0 + SS1[t] * i1;
    out[t] = v > 0.f ? v : 0.f;
}

extern "C" void kernel_launch(void* const* d_in, const int* in_sizes, int n_in,
                              void* d_out, int out_size, void* d_ws, size_t ws_size,
                              hipStream_t stream)
{
    const float* feat_P = (const float*)d_in[0];
    const float* feat_A = (const float*)d_in[1];
    const float* feat_state = (const float*)d_in[2];
    const float* W_P   = (const float*)d_in[3];  const float* b_P   = (const float*)d_in[4];
    const float* W_A   = (const float*)d_in[5];  const float* b_A   = (const float*)d_in[6];
    const float* W_p2p = (const float*)d_in[7];  const float* b_p2p = (const float*)d_in[8];
    const float* W_p2a = (const float*)d_in[9];  const float* b_p2a = (const float*)d_in[10];
    const float* W_a2p = (const float*)d_in[11]; const float* b_a2p = (const float*)d_in[12];
    const float* W_a2a = (const float*)d_in[13]; const float* b_a2a = (const float*)d_in[14];
    const float* W_p2s = (const float*)d_in[15]; const float* b_p2s = (const float*)d_in[16];
    const float* W_a2s = (const float*)d_in[17]; const float* b_a2s = (const float*)d_in[18];
    const float* W_in  = (const float*)d_in[19]; const float* b_in  = (const float*)d_in[20];
    const float* at_p2p_s = (const float*)d_in[21]; const float* at_p2p_d = (const float*)d_in[22];
    const float* at_p2a_s = (const float*)d_in[23]; const float* at_p2a_d = (const float*)d_in[24];
    const float* at_a2p_s = (const float*)d_in[25]; const float* at_a2p_d = (const float*)d_in[26];
    const float* at_a2a_s = (const float*)d_in[27]; const float* at_a2a_d = (const float*)d_in[28];
    const float* at_p2s_s = (const float*)d_in[29]; const float* at_p2s_d = (const float*)d_in[30];
    const float* at_a2s_s = (const float*)d_in[31]; const float* at_a2s_d = (const float*)d_in[32];
    const int* src_p2p = (const int*)d_in[33]; const int* dst_p2p = (const int*)d_in[34];
    const int* src_p2a = (const int*)d_in[35]; const int* dst_p2a = (const int*)d_in[36];
    const int* src_a2p = (const int*)d_in[37]; const int* dst_a2p = (const int*)d_in[38];
    const int* src_a2a = (const int*)d_in[39]; const int* dst_a2a = (const int*)d_in[40];
    float* out = (float*)d_out;

    // ---------------- workspace layout (all chunks 16B-multiple) ----------------
    char* base = (char*)d_ws;
    float* WhT    = (float*)base;  base += (size_t)NP * HD * 4;   // 15.36 MB
    float* w4     = (float*)base;  base += (size_t)EDG * 4 * 4;   // 6.4 MB
    int*   srcs   = (int*)base;    base += (size_t)EDG * 4;       // 1.6 MB
    float* ed_p2p = (float*)base;  base += NP * 4 * 4;
    float* ed_a2p = (float*)base;  base += NP * 4 * 4;
    float* ed_p2a = (float*)base;  base += NA * 4 * 4;
    float* ed_a2a = (float*)base;  base += NA * 4 * 4;
    float* es     = (float*)base;  base += NP * 4 * 4;
    int*   counts = (int*)base;    base += 4 * NODE_STRIDE * 4;   // 4 edge types
    int*   cursor = (int*)base;    base += 4 * NODE_STRIDE * 4;
    int*   offs   = (int*)base;    base += 4 * NODE_STRIDE * 4;
    float* Wh_inb = (float*)base;  base += 128 * 4;
    float* SS0    = (float*)base;  base += 128 * 4;
    float* SS1    = (float*)base;  base += 128 * 4;
    float* dS0    = (float*)base;  base += 4 * 4;
    float* dS1    = (float*)base;  base += 4 * 4;
    float* edsP   = (float*)base;  base += 4 * 4;
    float* edsA   = (float*)base;  base += 4 * 4;
    size_t needed = (size_t)(base - (char*)d_ws);
    if (ws_size < needed) return;   // diagnostic guard: fail validation, not the container

    int* cnt_p2p = counts;                 int* cur_p2p = cursor;                 int* off_p2p = offs;
    int* cnt_a2p = counts + NODE_STRIDE;   int* cur_a2p = cursor + NODE_STRIDE;   int* off_a2p = offs + NODE_STRIDE;
    int* cnt_p2a = counts + 2*NODE_STRIDE; int* cur_p2a = cursor + 2*NODE_STRIDE; int* off_p2a = offs + 2*NODE_STRIDE;
    int* cnt_a2a = counts + 3*NODE_STRIDE; int* cur_a2a = cursor + 3*NODE_STRIDE; int* off_a2a = offs + 3*NODE_STRIDE;

    float* outP = out;
    float* outA = out + (size_t)NP * HD;
    float* outS = out + (size_t)(NP + NA) * HD;

    const dim3 B(256);
    const int gGemm = (NP + 63) / 64;
    const int gNodeW64 = (NP * 64 + 255) / 256;
    const int gEdgeT = (EDG + 255) / 256;

    // ---- CSR builds (depend only on dst index arrays) ----
    hipMemsetAsync(counts, 0, 4 * NODE_STRIDE * sizeof(int), stream);
    hist_dst<<<gEdgeT, B, 0, stream>>>(dst_p2p, cnt_p2p, EDG);
    hist_dst<<<gEdgeT, B, 0, stream>>>(dst_a2p, cnt_a2p, EDG);
    hist_dst<<<gEdgeT, B, 0, stream>>>(dst_p2a, cnt_p2a, EDG);
    hist_dst<<<gEdgeT, B, 0, stream>>>(dst_a2a, cnt_a2a, EDG);
    scan4<<<4, 1024, 0, stream>>>(counts, offs, cursor, NP);

    state_lin<<<1, 128, 0, stream>>>(feat_state, W_in, b_in, Wh_inb, 64);
    edot2<<<1, 128, 0, stream>>>(Wh_inb, at_p2s_d, at_a2s_d, edsP, edsA);

    // ================= phase P (Wh_P lives directly in outP) =================
    gemm_rd<2><<<gGemm, B, 0, stream>>>(feat_P, W_P, b_P, outP, NP,
                                        at_p2p_d, ed_p2p, at_a2p_d, ed_a2p);
    // p2p
    gemm_rd<1><<<gGemm, B, 0, stream>>>(feat_P, W_p2p, b_p2p, WhT, NP,
                                        at_p2p_s, es, nullptr, nullptr);
    scatter_edges<<<gEdgeT, B, 0, stream>>>(src_p2p, dst_p2p, es, ed_p2p, cur_p2p, srcs, w4, EDG);
    aggregate_add<0><<<gNodeW64, B, 0, stream>>>(WhT, off_p2p, srcs, w4, outP, NP);
    // a2p
    gemm_rd<1><<<gGemm, B, 0, stream>>>(feat_A, W_a2p, b_a2p, WhT, NA,
                                        at_a2p_s, es, nullptr, nullptr);
    scatter_edges<<<gEdgeT, B, 0, stream>>>(src_a2p, dst_a2p, es, ed_a2p, cur_a2p, srcs, w4, EDG);
    aggregate_add<1><<<gNodeW64, B, 0, stream>>>(WhT, off_a2p, srcs, w4, outP, NP);

    // ================= phase A (Wh_A lives directly in outA) =================
    gemm_rd<2><<<gGemm, B, 0, stream>>>(feat_A, W_A, b_A, outA, NA,
                                        at_p2a_d, ed_p2a, at_a2a_d, ed_a2a);
    // p2a
    gemm_rd<1><<<gGemm, B, 0, stream>>>(feat_P, W_p2a, b_p2a, WhT, NP,
                                        at_p2a_s, es, nullptr, nullptr);
    scatter_edges<<<gEdgeT, B, 0, stream>>>(src_p2a, dst_p2a, es, ed_p2a, cur_p2a, srcs, w4, EDG);
    aggregate_add<0><<<gNodeW64, B, 0, stream>>>(WhT, off_p2a, srcs, w4, outA, NA);
    // a2a
    gemm_rd<1><<<gGemm, B, 0, stream>>>(feat_A, W_a2a, b_a2a, WhT, NA,
                                        at_a2a_s, es, nullptr, nullptr);
    scatter_edges<<<gEdgeT, B, 0, stream>>>(src_a2a, dst_a2a, es, ed_a2a, cur_a2a, srcs, w4, EDG);
    aggregate_add<1><<<gNodeW64, B, 0, stream>>>(WhT, off_a2a, srcs, w4, outA, NA);

    // ================= state (p2s / a2s; all edges -> single node 0) =================
    hipMemsetAsync(SS0, 0, (128 + 128 + 4 + 4) * sizeof(float), stream);  // SS0,SS1,dS0,dS1
    gemm_state<<<gGemm, B, 0, stream>>>(feat_P, W_p2s, b_p2s, NP, at_p2s_s, edsP, SS0, dS0);
    gemm_state<<<gGemm, B, 0, stream>>>(feat_A, W_a2s, b_a2s, NA, at_a2s_s, edsA, SS1, dS1);
    finalize_state<<<1, 128, 0, stream>>>(Wh_inb, SS0, dS0, SS1, dS1, outS);
}

// Round 7
// 742.708 us; speedup vs baseline: 1.2774x; 1.0730x over previous
//
#include <hip/hip_runtime.h>

#define NP 30000
#define NA 30000
#define EDG 400000
#define HD 128          // H*D
#define LRELU_ALPHA 0.2f
#define NODE_STRIDE 30016   // padded per-type stride for count/cursor/offset arrays (ints)
#define TILE 32             // rows per GEMM block (8 rows/thread, 4 waves)
#define BPJ 938             // blocks per GEMM job = ceil(30000/32)

__device__ __forceinline__ float lrelu(float x) { return x > 0.f ? x : LRELU_ALPHA * x; }

// ---------------- batched GEMM with per-job epilogue ----------------
// Each job: C[30000][128] = A[30000][128] @ W[128][128] + b, 32-row tiles,
// block 256 = 4 waves; thread: 8 rows x 2 cols (cg, cg+64); wave rg owns rows
// rg*8..+7 entirely -> per-row dots via 32-wide shuffle butterflies.
// mode 0: write C + rowdot with a1->o1 and a2->o2   (self transforms)
// mode 1: write C + rowdot with a1->o1              (edge-type tables)
// mode 2: NO C write; state aggregation: a1=attn_src vec, a2=eds[4],
//         o1=SS[128] (atomic), o2=dS[4] (atomic)    (p2s/a2s fused)
struct GJob {
    const float* A; const float* W; const float* bias;
    float* C;
    const float* a1; float* o1;
    const float* a2; float* o2;
    int mode;
};
struct GJobs { GJob j[4]; };

__launch_bounds__(256)
__global__ void gemm_multi(GJobs js)
{
    const GJob J = js.j[blockIdx.y];
    __shared__ float As[TILE * 128];
    __shared__ float red[4][128];     // state-mode block reduce (separate from As:
    __shared__ float dred[4][4];      //  no barrier between k-loop and epilogue)
    const int t = threadIdx.x;
    const int row0 = blockIdx.x * TILE;
    const int M = NP;                 // all jobs are 30000 rows
    #pragma unroll
    for (int i = 0; i < 4; ++i) {
        int f4 = t + i * 256;            // 0..1023 float4 slots
        int r = f4 >> 5, c4 = f4 & 31;
        int gr = row0 + r;
        float4 v = make_float4(0.f, 0.f, 0.f, 0.f);
        if (gr < M) v = reinterpret_cast<const float4*>(J.A)[(size_t)gr * 32 + c4];
        reinterpret_cast<float4*>(As)[f4] = v;
    }
    __syncthreads();
    const int cg = t & 63;   // cols cg and cg+64
    const int rg = t >> 6;   // wave id; rows rg*8 .. rg*8+7
    float acc0[8], acc1[8];
    #pragma unroll
    for (int r = 0; r < 8; ++r) { acc0[r] = 0.f; acc1[r] = 0.f; }
    const float* Asr = &As[rg * 8 * 128];
    const float* W = J.W;
    for (int k = 0; k < 128; k += 4) {
        float w00 = W[(k+0)*128 + cg],    w01 = W[(k+1)*128 + cg],
              w02 = W[(k+2)*128 + cg],    w03 = W[(k+3)*128 + cg];
        float w10 = W[(k+0)*128 + cg+64], w11 = W[(k+1)*128 + cg+64],
              w12 = W[(k+2)*128 + cg+64], w13 = W[(k+3)*128 + cg+64];
        #pragma unroll
        for (int r = 0; r < 8; ++r) {
            float4 f = *reinterpret_cast<const float4*>(&Asr[r * 128 + k]);
            acc0[r] += f.x*w00 + f.y*w01 + f.z*w02 + f.w*w03;
            acc1[r] += f.x*w10 + f.y*w11 + f.z*w12 + f.w*w13;
        }
    }
    float b0 = J.bias[cg], b1 = J.bias[cg + 64];
    #pragma unroll
    for (int r = 0; r < 8; ++r) { acc0[r] += b0; acc1[r] += b1; }

    if (J.mode != 2) {
        // ---- C write ----
        #pragma unroll
        for (int r = 0; r < 8; ++r) {
            int gr = row0 + rg * 8 + r;
            if (gr < M) {
                J.C[(size_t)gr * 128 + cg]      = acc0[r];
                J.C[(size_t)gr * 128 + cg + 64] = acc1[r];
            }
        }
        // ---- rowdot epilogue (1 or 2 attention vectors) ----
        const int nrd = (J.mode == 0) ? 2 : 1;
        float a10 = J.a1[cg], a11 = J.a1[cg + 64];
        float a20 = 0.f, a21 = 0.f;
        if (nrd == 2) { a20 = J.a2[cg]; a21 = J.a2[cg + 64]; }
        #pragma unroll
        for (int r = 0; r < 8; ++r) {
            int node = row0 + rg * 8 + r;
            if (node >= M) break;      // wave-uniform
            float t10 = acc0[r] * a10, t11 = acc1[r] * a11;
            float t20 = acc0[r] * a20, t21 = acc1[r] * a21;
            #pragma unroll
            for (int off = 16; off; off >>= 1) {
                t10 += __shfl_xor(t10, off, 32);
                t11 += __shfl_xor(t11, off, 32);
                t20 += __shfl_xor(t20, off, 32);
                t21 += __shfl_xor(t21, off, 32);
            }
            // lanes 0..31 hold heads 0/2; lanes 32..63 hold heads 1/3
            if (cg == 0)  { J.o1[node*4+0] = t10; J.o1[node*4+2] = t11;
                            if (nrd == 2) { J.o2[node*4+0] = t20; J.o2[node*4+2] = t21; } }
            if (cg == 32) { J.o1[node*4+1] = t10; J.o1[node*4+3] = t11;
                            if (nrd == 2) { J.o2[node*4+1] = t20; J.o2[node*4+3] = t21; } }
        }
    } else {
        // ---- state aggregation epilogue (no C write) ----
        float av0 = J.a1[cg], av1 = J.a1[cg + 64];
        float e0 = J.a2[cg >> 5];        // head of col cg (0 or 1)
        float e1 = J.a2[2 + (cg >> 5)];  // head of col cg+64 (2 or 3)
        float sacc0 = 0.f, sacc1 = 0.f, ds0 = 0.f, ds1 = 0.f;
        #pragma unroll
        for (int r = 0; r < 8; ++r) {
            int node = row0 + rg * 8 + r;
            if (node >= M) break;       // wave-uniform
            float f0 = acc0[r], f1 = acc1[r];
            float t0 = f0 * av0, t1 = f1 * av1;
            #pragma unroll
            for (int off = 16; off; off >>= 1) {
                t0 += __shfl_xor(t0, off, 32);
                t1 += __shfl_xor(t1, off, 32);
            }
            float w0 = __expf(lrelu(t0 + e0));   // 32-lane group shares w
            float w1 = __expf(lrelu(t1 + e1));
            sacc0 += w0 * f0; sacc1 += w1 * f1;
            ds0 += w0; ds1 += w1;
        }
        red[rg][cg] = sacc0;
        red[rg][cg + 64] = sacc1;
        if (cg == 0)  { dred[rg][0] = ds0; dred[rg][2] = ds1; }
        if (cg == 32) { dred[rg][1] = ds0; dred[rg][3] = ds1; }
        __syncthreads();
        if (t < 128) {
            float s = red[0][t] + red[1][t] + red[2][t] + red[3][t];
            atomicAdd(&J.o1[t], s);
        }
        if (t < 4) {
            float s = dred[0][t] + dred[1][t] + dred[2][t] + dred[3][t];
            atomicAdd(&J.o2[t], s);
        }
    }
}

// ---------------- state linear: out[128] = feat[K] @ W[K][128] + b ----------------
__global__ void state_lin(const float* __restrict__ feat, const float* __restrict__ W,
                          const float* __restrict__ b, float* __restrict__ out, int K)
{
    int n = threadIdx.x;   // 128 threads
    float acc = b[n];
    for (int k = 0; k < K; ++k) acc += feat[k] * W[k * 128 + n];
    out[n] = acc;
}

// ---- tiny: per-head dots of Wh_in with the two state dst-attn vectors ----
__global__ void edot2(const float* __restrict__ Wh_inb, const float* __restrict__ aP,
                      const float* __restrict__ aA, float* __restrict__ edsP,
                      float* __restrict__ edsA)
{
    int t = threadIdx.x;   // 128
    int l = t & 31;
    float v = Wh_inb[t];
    float p = v * aP[t];
    float q = v * aA[t];
    #pragma unroll
    for (int off = 16; off; off >>= 1) {
        p += __shfl_xor(p, off, 32);
        q += __shfl_xor(q, off, 32);
    }
    if (l == 0) { edsP[t >> 5] = p; edsA[t >> 5] = q; }
}

// ---------------- CSR build: 4-way batched histogram / scatter ----------------
struct EdgeJobs { const int* src[4]; const int* dst[4]; int* srcsOut[4]; };

__launch_bounds__(256)
__global__ void hist4(EdgeJobs ej, int* __restrict__ counts)
{
    int y = blockIdx.y;
    int e = blockIdx.x * 256 + threadIdx.x;
    if (e < EDG) atomicAdd(&counts[y * NODE_STRIDE + ej.dst[y][e]], 1);
}

// scan counts -> offsets + cursor. grid = 4 blocks (one per edge type), 1024 thr.
__launch_bounds__(1024)
__global__ void scan4(const int* __restrict__ counts, int* __restrict__ offsets,
                      int* __restrict__ cursor, int n)
{
    const int* cnt = counts + blockIdx.x * NODE_STRIDE;
    int* off = offsets + blockIdx.x * NODE_STRIDE;
    int* cur = cursor + blockIdx.x * NODE_STRIDE;
    int t = threadIdx.x;
    int lane = t & 63, wv = t >> 6;
    __shared__ int wsum[16];
    __shared__ int carry_s;
    if (t == 0) { carry_s = 0; off[0] = 0; }
    __syncthreads();
    for (int base = 0; base < n; base += 1024) {
        int i = base + t;
        int v = (i < n) ? cnt[i] : 0;
        int x = v;
        #pragma unroll
        for (int o = 1; o < 64; o <<= 1) {
            int y = __shfl_up(x, o, 64);
            if (lane >= o) x += y;
        }
        if (lane == 63) wsum[wv] = x;
        __syncthreads();
        if (wv == 0) {
            int y = (lane < 16) ? wsum[lane] : 0;
            #pragma unroll
            for (int o = 1; o < 16; o <<= 1) {
                int z = __shfl_up(y, o, 64);
                if (lane >= o) y += z;
            }
            if (lane < 16) wsum[lane] = y;
        }
        __syncthreads();
        int add = carry_s + (wv > 0 ? wsum[wv - 1] : 0);
        int incl = x + add;
        if (i < n) { off[i + 1] = incl; cur[i] = incl - v; }
        __syncthreads();
        if (t == 0) carry_s += wsum[15];
        __syncthreads();
    }
}

// pure permutation: srcsOut[csr_pos] = src  (w recomputed later in aggregate)
__launch_bounds__(256)
__global__ void scatter4(EdgeJobs ej, int* __restrict__ cursor)
{
    int y = blockIdx.y;
    int e = blockIdx.x * 256 + threadIdx.x;
    if (e >= EDG) return;
    int d = ej.dst[y][e];
    int pos = atomicAdd(&cursor[y * NODE_STRIDE + d], 1);
    ej.srcsOut[y][pos] = ej.src[y][e];
}

// ---- aggregate BOTH edge types for a node type; normalize, add self, relu ----
// one 64-lane wave per dst node; lane owns features 2*lane..2*lane+1 (head=lane>>4).
// w recomputed inline: w = exp(lrelu(es[src*4+h] + ed[node*4+h])).
__launch_bounds__(256)
__global__ void aggregate2(const float* __restrict__ Wh0, const int* __restrict__ off0,
                           const int* __restrict__ srcs0, const float* __restrict__ es0,
                           const float* __restrict__ ed0,
                           const float* __restrict__ Wh1, const int* __restrict__ off1,
                           const int* __restrict__ srcs1, const float* __restrict__ es1,
                           const float* __restrict__ ed1,
                           float* __restrict__ out, int n)
{
    int lane = threadIdx.x & 63;
    int node = (blockIdx.x * blockDim.x + threadIdx.x) >> 6;
    if (node >= n) return;
    const int h = lane >> 4;
    float accX0 = 0.f, accY0 = 0.f, d0 = 0.f;
    float accX1 = 0.f, accY1 = 0.f, d1 = 0.f;
    {
        float edv = ed0[node * 4 + h];
        int b = off0[node], e = off0[node + 1];
        int i = b;
        for (; i + 4 <= e; i += 4) {
            int s0 = srcs0[i], s1 = srcs0[i+1], s2 = srcs0[i+2], s3 = srcs0[i+3];
            float w0 = __expf(lrelu(es0[s0*4 + h] + edv));
            float w1 = __expf(lrelu(es0[s1*4 + h] + edv));
            float w2 = __expf(lrelu(es0[s2*4 + h] + edv));
            float w3 = __expf(lrelu(es0[s3*4 + h] + edv));
            float2 x0 = *reinterpret_cast<const float2*>(&Wh0[(size_t)s0*128 + lane*2]);
            float2 x1 = *reinterpret_cast<const float2*>(&Wh0[(size_t)s1*128 + lane*2]);
            float2 x2 = *reinterpret_cast<const float2*>(&Wh0[(size_t)s2*128 + lane*2]);
            float2 x3 = *reinterpret_cast<const float2*>(&Wh0[(size_t)s3*128 + lane*2]);
            accX0 += w0*x0.x + w1*x1.x + w2*x2.x + w3*x3.x;
            accY0 += w0*x0.y + w1*x1.y + w2*x2.y + w3*x3.y;
            d0 += w0 + w1 + w2 + w3;
        }
        for (; i < e; ++i) {
            int s = srcs0[i];
            float w = __expf(lrelu(es0[s*4 + h] + edv));
            float2 x = *reinterpret_cast<const float2*>(&Wh0[(size_t)s*128 + lane*2]);
            accX0 += w * x.x; accY0 += w * x.y; d0 += w;
        }
    }
    {
        float edv = ed1[node * 4 + h];
        int b = off1[node], e = off1[node + 1];
        int i = b;
        for (; i + 4 <= e; i += 4) {
            int s0 = srcs1[i], s1 = srcs1[i+1], s2 = srcs1[i+2], s3 = srcs1[i+3];
            float w0 = __expf(lrelu(es1[s0*4 + h] + edv));
            float w1 = __expf(lrelu(es1[s1*4 + h] + edv));
            float w2 = __expf(lrelu(es1[s2*4 + h] + edv));
            float w3 = __expf(lrelu(es1[s3*4 + h] + edv));
            float2 x0 = *reinterpret_cast<const float2*>(&Wh1[(size_t)s0*128 + lane*2]);
            float2 x1 = *reinterpret_cast<const float2*>(&Wh1[(size_t)s1*128 + lane*2]);
            float2 x2 = *reinterpret_cast<const float2*>(&Wh1[(size_t)s2*128 + lane*2]);
            float2 x3 = *reinterpret_cast<const float2*>(&Wh1[(size_t)s3*128 + lane*2]);
            accX1 += w0*x0.x + w1*x1.x + w2*x2.x + w3*x3.x;
            accY1 += w0*x0.y + w1*x1.y + w2*x2.y + w3*x3.y;
            d1 += w0 + w1 + w2 + w3;
        }
        for (; i < e; ++i) {
            int s = srcs1[i];
            float w = __expf(lrelu(es1[s*4 + h] + edv));
            float2 x = *reinterpret_cast<const float2*>(&Wh1[(size_t)s*128 + lane*2]);
            accX1 += w * x.x; accY1 += w * x.y; d1 += w;
        }
    }
    float i0 = d0 > 0.f ? 1.f / d0 : 0.f;
    float i1 = d1 > 0.f ? 1.f / d1 : 0.f;
    float2* op = reinterpret_cast<float2*>(out + (size_t)node * 128) + lane;
    float2 o = *op;
    o.x += accX0 * i0 + accX1 * i1;
    o.y += accY0 * i0 + accY1 * i1;
    o.x = o.x > 0.f ? o.x : 0.f;
    o.y = o.y > 0.f ? o.y : 0.f;
    *op = o;
}

__global__ void finalize_state(const float* __restrict__ Wh_in, const float* __restrict__ SS0,
                               const float* __restrict__ dS0, const float* __restrict__ SS1,
                               const float* __restrict__ dS1, float* __restrict__ out)
{
    int t = threadIdx.x;   // 128
    int h = t >> 5;
    float v0 = dS0[h]; float i0 = v0 > 0.f ? 1.f / v0 : 0.f;
    float v1 = dS1[h]; float i1 = v1 > 0.f ? 1.f / v1 : 0.f;
    float v = Wh_in[t] + SS0[t] * i0 + SS1[t] * i1;
    out[t] = v > 0.f ? v : 0.f;
}

extern "C" void kernel_launch(void* const* d_in, const int* in_sizes, int n_in,
                              void* d_out, int out_size, void* d_ws, size_t ws_size,
                              hipStream_t stream)
{
    const float* feat_P = (const float*)d_in[0];
    const float* feat_A = (const float*)d_in[1];
    const float* feat_state = (const float*)d_in[2];
    const float* W_P   = (const float*)d_in[3];  const float* b_P   = (const float*)d_in[4];
    const float* W_A   = (const float*)d_in[5];  const float* b_A   = (const float*)d_in[6];
    const float* W_p2p = (const float*)d_in[7];  const float* b_p2p = (const float*)d_in[8];
    const float* W_p2a = (const float*)d_in[9];  const float* b_p2a = (const float*)d_in[10];
    const float* W_a2p = (const float*)d_in[11]; const float* b_a2p = (const float*)d_in[12];
    const float* W_a2a = (const float*)d_in[13]; const float* b_a2a = (const float*)d_in[14];
    const float* W_p2s = (const float*)d_in[15]; const float* b_p2s = (const float*)d_in[16];
    const float* W_a2s = (const float*)d_in[17]; const float* b_a2s = (const float*)d_in[18];
    const float* W_in  = (const float*)d_in[19]; const float* b_in  = (const float*)d_in[20];
    const float* at_p2p_s = (const float*)d_in[21]; const float* at_p2p_d = (const float*)d_in[22];
    const float* at_p2a_s = (const float*)d_in[23]; const float* at_p2a_d = (const float*)d_in[24];
    const float* at_a2p_s = (const float*)d_in[25]; const float* at_a2p_d = (const float*)d_in[26];
    const float* at_a2a_s = (const float*)d_in[27]; const float* at_a2a_d = (const float*)d_in[28];
    const float* at_p2s_s = (const float*)d_in[29]; const float* at_p2s_d = (const float*)d_in[30];
    const float* at_a2s_s = (const float*)d_in[31]; const float* at_a2s_d = (const float*)d_in[32];
    const int* src_p2p = (const int*)d_in[33]; const int* dst_p2p = (const int*)d_in[34];
    const int* src_p2a = (const int*)d_in[35]; const int* dst_p2a = (const int*)d_in[36];
    const int* src_a2p = (const int*)d_in[37]; const int* dst_a2p = (const int*)d_in[38];
    const int* src_a2a = (const int*)d_in[39]; const int* dst_a2a = (const int*)d_in[40];
    float* out = (float*)d_out;

    // ---------------- workspace layout (all chunks 16B-multiple) ----------------
    char* base = (char*)d_ws;
    float* WhT0   = (float*)base;  base += (size_t)NP * HD * 4;   // 15.36 MB
    float* WhT1   = (float*)base;  base += (size_t)NP * HD * 4;   // 15.36 MB
    int* srcs_p2p = (int*)base;    base += (size_t)EDG * 4;       // 1.6 MB each
    int* srcs_a2p = (int*)base;    base += (size_t)EDG * 4;
    int* srcs_p2a = (int*)base;    base += (size_t)EDG * 4;
    int* srcs_a2a = (int*)base;    base += (size_t)EDG * 4;
    float* es_p2p = (float*)base;  base += NP * 4 * 4;            // 480 KB each
    float* es_a2p = (float*)base;  base += NA * 4 * 4;
    float* es_p2a = (float*)base;  base += NP * 4 * 4;
    float* es_a2a = (float*)base;  base += NA * 4 * 4;
    float* ed_p2p = (float*)base;  base += NP * 4 * 4;
    float* ed_a2p = (float*)base;  base += NP * 4 * 4;
    float* ed_p2a = (float*)base;  base += NA * 4 * 4;
    float* ed_a2a = (float*)base;  base += NA * 4 * 4;
    int*   counts = (int*)base;    base += 4 * NODE_STRIDE * 4;
    int*   cursor = (int*)base;    base += 4 * NODE_STRIDE * 4;
    int*   offs   = (int*)base;    base += 4 * NODE_STRIDE * 4;
    float* Wh_inb = (float*)base;  base += 128 * 4;
    float* SS0    = (float*)base;  base += 128 * 4;               // SS0,SS1,dS0,dS1 contiguous (memset)
    float* SS1    = (float*)base;  base += 128 * 4;
    float* dS0    = (float*)base;  base += 4 * 4;
    float* dS1    = (float*)base;  base += 4 * 4;
    float* edsP   = (float*)base;  base += 4 * 4;
    float* edsA   = (float*)base;  base += 4 * 4;
    size_t needed = (size_t)(base - (char*)d_ws);   // ~42.4 MB
    if (ws_size < needed) return;   // diagnostic guard: fail validation, not the container

    // CSR slot order: 0=p2p, 1=a2p, 2=p2a, 3=a2a
    int* off_p2p = offs;
    int* off_a2p = offs + NODE_STRIDE;
    int* off_p2a = offs + 2 * NODE_STRIDE;
    int* off_a2a = offs + 3 * NODE_STRIDE;

    float* outP = out;
    float* outA = out + (size_t)NP * HD;
    float* outS = out + (size_t)(NP + NA) * HD;

    const dim3 B(256);
    const int gNodeW64 = (NP * 64 + 255) / 256;   // 7500
    const int gEdgeT = (EDG + 255) / 256;         // 1563

    // ---- CSR build (independent of all GEMMs) ----
    EdgeJobs ej;
    ej.src[0] = src_p2p; ej.dst[0] = dst_p2p; ej.srcsOut[0] = srcs_p2p;
    ej.src[1] = src_a2p; ej.dst[1] = dst_a2p; ej.srcsOut[1] = srcs_a2p;
    ej.src[2] = src_p2a; ej.dst[2] = dst_p2a; ej.srcsOut[2] = srcs_p2a;
    ej.src[3] = src_a2a; ej.dst[3] = dst_a2a; ej.srcsOut[3] = srcs_a2a;
    hipMemsetAsync(counts, 0, 4 * NODE_STRIDE * sizeof(int), stream);
    hist4<<<dim3(gEdgeT, 4), B, 0, stream>>>(ej, counts);
    scan4<<<4, 1024, 0, stream>>>(counts, offs, cursor, NP);
    scatter4<<<dim3(gEdgeT, 4), B, 0, stream>>>(ej, cursor);

    // ---- state prologue ----
    hipMemsetAsync(SS0, 0, (128 + 128 + 4 + 4) * sizeof(float), stream);
    state_lin<<<1, 128, 0, stream>>>(feat_state, W_in, b_in, Wh_inb, 64);
    edot2<<<1, 128, 0, stream>>>(Wh_inb, at_p2s_d, at_a2s_d, edsP, edsA);

    // ---- G1: selfP, selfA, p2p->WhT0, a2p->WhT1 (one dispatch, 3752 blocks) ----
    {
        GJobs g;
        g.j[0] = { feat_P, W_P,   b_P,   outP, at_p2p_d, ed_p2p, at_a2p_d, ed_a2p, 0 };
        g.j[1] = { feat_A, W_A,   b_A,   outA, at_p2a_d, ed_p2a, at_a2a_d, ed_a2a, 0 };
        g.j[2] = { feat_P, W_p2p, b_p2p, WhT0, at_p2p_s, es_p2p, nullptr,  nullptr, 1 };
        g.j[3] = { feat_A, W_a2p, b_a2p, WhT1, at_a2p_s, es_a2p, nullptr,  nullptr, 1 };
        gemm_multi<<<dim3(BPJ, 4), B, 0, stream>>>(g);
    }
    // ---- aggregate p2p + a2p into outP (+relu) ----
    aggregate2<<<gNodeW64, B, 0, stream>>>(WhT0, off_p2p, srcs_p2p, es_p2p, ed_p2p,
                                           WhT1, off_a2p, srcs_a2p, es_a2p, ed_a2p,
                                           outP, NP);

    // ---- G2: p2a->WhT0, a2a->WhT1, stateP, stateA ----
    {
        GJobs g;
        g.j[0] = { feat_P, W_p2a, b_p2a, WhT0,    at_p2a_s, es_p2a, nullptr, nullptr, 1 };
        g.j[1] = { feat_A, W_a2a, b_a2a, WhT1,    at_a2a_s, es_a2a, nullptr, nullptr, 1 };
        g.j[2] = { feat_P, W_p2s, b_p2s, nullptr, at_p2s_s, SS0,    edsP,    dS0,     2 };
        g.j[3] = { feat_A, W_a2s, b_a2s, nullptr, at_a2s_s, SS1,    edsA,    dS1,     2 };
        gemm_multi<<<dim3(BPJ, 4), B, 0, stream>>>(g);
    }
    // ---- aggregate p2a + a2a into outA (+relu) ----
    aggregate2<<<gNodeW64, B, 0, stream>>>(WhT0, off_p2a, srcs_p2a, es_p2a, ed_p2a,
                                           WhT1, off_a2a, srcs_a2a, es_a2a, ed_a2a,
                                           outA, NA);

    finalize_state<<<1, 128, 0, stream>>>(Wh_inb, SS0, dS0, SS1, dS1, outS);
}

// Round 8
// 636.517 us; speedup vs baseline: 1.4905x; 1.1668x over previous
//
#include <hip/hip_runtime.h>

#define NP 30000
#define NA 30000
#define EDG 400000
#define HD 128          // H*D
#define LRELU_ALPHA 0.2f
#define NODE_STRIDE 30016   // padded per-type stride for count/cursor/offset arrays (ints)
#define TILE 32             // rows per fp32-GEMM block (8 rows/thread, 4 waves)
#define BPJ 938             // blocks per fp32-GEMM job = ceil(30000/32)
#define MTILE 64            // rows per MFMA block
#define MBPJ 469            // ceil(30000/64)
#define WS_OFF 16384        // byte offset of W region in MFMA LDS

typedef __attribute__((ext_vector_type(8))) short short8;
typedef __attribute__((ext_vector_type(4))) float f32x4;

__device__ __forceinline__ float lrelu(float x) { return x > 0.f ? x : LRELU_ALPHA * x; }

// float -> bf16 with round-to-nearest-even (inputs finite)
__device__ __forceinline__ unsigned short f2bf(float f) {
    unsigned u = __float_as_uint(f);
    u += 0x7fffu + ((u >> 16) & 1u);
    return (unsigned short)(u >> 16);
}

// ================= MFMA bf16 GEMM for the 4 edge-type tables =================
// job: C_bf16[30000][128] = bf16(A[30000][128]) @ bf16(W[128][128]) + b, plus
// es[node][h] = dot(Wh_row[h*32..], a1[h*32..]) from fp32 accumulators.
// Block 256 thr = 4 waves; wave w owns rows w*16..w*16+15 of a 64-row tile;
// 8 col-tiles of 16; K=128 in 4 chunks of 32 (mfma_f32_16x16x32_bf16).
// LDS: A-tile bf16 [64][128] (16KB) + W^T bf16 [128][128] (32KB), both stored
// row-stride 256B with 16B-unit XOR swizzle (byte ^= (row&7)<<4) so the
// 16-lane frag reads (consecutive rows, same k-chunk) spread across banks.
struct MJob {
    const float* A; const float* W; const float* bias;
    unsigned short* C; const float* a1; float* es;
};
struct MJobs { MJob j[4]; };

__launch_bounds__(256)
__global__ void gemm_mfma(MJobs js)
{
    const MJob J = js.j[blockIdx.y];
    __shared__ alignas(16) char lds[49152];
    const int t = threadIdx.x;
    const int row0 = blockIdx.x * MTILE;
    const int M = NP;

    // ---- stage A tile: fp32 -> bf16, swizzled ----
    #pragma unroll
    for (int i = 0; i < 4; ++i) {
        int c = t + i * 256;            // 1024 chunks of 8 elements
        int row = c >> 4, k0 = (c & 15) * 8;
        int gr = row0 + row;
        float4 v0 = make_float4(0.f,0.f,0.f,0.f), v1 = v0;
        if (gr < M) {
            v0 = reinterpret_cast<const float4*>(J.A)[(size_t)gr * 32 + (k0 >> 2)];
            v1 = reinterpret_cast<const float4*>(J.A)[(size_t)gr * 32 + (k0 >> 2) + 1];
        }
        short8 p;
        p[0]=f2bf(v0.x); p[1]=f2bf(v0.y); p[2]=f2bf(v0.z); p[3]=f2bf(v0.w);
        p[4]=f2bf(v1.x); p[5]=f2bf(v1.y); p[6]=f2bf(v1.z); p[7]=f2bf(v1.w);
        int byte = (row * 256 + k0 * 2) ^ ((row & 7) << 4);
        *reinterpret_cast<short8*>(lds + byte) = p;
    }
    // ---- stage W transposed: WsT[col][k] = W[k][col], fp32 -> bf16, swizzled ----
    {
        int c4 = (t & 31) * 4;          // 4 columns
        int kk = (t >> 5) * 16;         // 16 k's
        unsigned short wb[4][16];
        #pragma unroll
        for (int k = 0; k < 16; ++k) {
            float4 v = reinterpret_cast<const float4*>(J.W)[(kk + k) * 32 + (c4 >> 2)];
            wb[0][k]=f2bf(v.x); wb[1][k]=f2bf(v.y); wb[2][k]=f2bf(v.z); wb[3][k]=f2bf(v.w);
        }
        #pragma unroll
        for (int j = 0; j < 4; ++j) {
            int col = c4 + j;
            short8 s0, s1;
            #pragma unroll
            for (int q = 0; q < 8; ++q) { s0[q] = (short)wb[j][q]; s1[q] = (short)wb[j][q+8]; }
            int inner = col * 256 + kk * 2;
            int x = (col & 7) << 4;
            *reinterpret_cast<short8*>(lds + WS_OFF + ((inner)      ^ x)) = s0;
            *reinterpret_cast<short8*>(lds + WS_OFF + ((inner + 16) ^ x)) = s1;
        }
    }
    __syncthreads();

    const int l = t & 63, w = t >> 6;
    f32x4 acc[8];
    #pragma unroll
    for (int ct = 0; ct < 8; ++ct) {
        float bv = J.bias[ct * 16 + (l & 15)];
        acc[ct] = (f32x4){bv, bv, bv, bv};
    }
    const int arow = w * 16 + (l & 15);
    const int abase = arow * 256 + ((l >> 4) * 16);
    const int axor = (arow & 7) << 4;
    const int bxor = ((l & 15) & 7) << 4;
    #pragma unroll
    for (int kc = 0; kc < 4; ++kc) {
        short8 af = *reinterpret_cast<const short8*>(lds + ((abase + kc * 64) ^ axor));
        #pragma unroll
        for (int ct = 0; ct < 8; ++ct) {
            int binner = (ct * 16 + (l & 15)) * 256 + kc * 64 + ((l >> 4) * 16);
            short8 bf8 = *reinterpret_cast<const short8*>(lds + WS_OFF + (binner ^ bxor));
            acc[ct] = __builtin_amdgcn_mfma_f32_16x16x32_bf16(af, bf8, acc[ct], 0, 0, 0);
        }
    }
    // ---- C store (bf16): lane holds rows (l>>4)*4+r, cols ct*16+(l&15) ----
    #pragma unroll
    for (int r = 0; r < 4; ++r) {
        int grow = row0 + w * 16 + (l >> 4) * 4 + r;
        if (grow < M) {
            #pragma unroll
            for (int ct = 0; ct < 8; ++ct)
                J.C[(size_t)grow * 128 + ct * 16 + (l & 15)] = f2bf(acc[ct][r]);
        }
    }
    // ---- es: per-head dots from fp32 acc; butterfly over the 16-lane group ----
    #pragma unroll
    for (int h = 0; h < 4; ++h) {
        float alo = J.a1[h * 32 + (l & 15)];
        float ahi = J.a1[h * 32 + 16 + (l & 15)];
        #pragma unroll
        for (int r = 0; r < 4; ++r) {
            float p = acc[2*h][r] * alo + acc[2*h+1][r] * ahi;
            p += __shfl_xor(p, 1); p += __shfl_xor(p, 2);
            p += __shfl_xor(p, 4); p += __shfl_xor(p, 8);
            int grow = row0 + w * 16 + (l >> 4) * 4 + r;
            if ((l & 15) == 0 && grow < M) J.es[grow * 4 + h] = p;
        }
    }
}

// ================= fp32 GEMM (selves + state path), as round 7 =================
// mode 0: write C + rowdot a1->o1, a2->o2 ; mode 2: state aggregation epilogue.
struct GJob {
    const float* A; const float* W; const float* bias;
    float* C;
    const float* a1; float* o1;
    const float* a2; float* o2;
    int mode;
};
struct GJobs { GJob j[4]; };

__launch_bounds__(256)
__global__ void gemm_multi(GJobs js)
{
    const GJob J = js.j[blockIdx.y];
    __shared__ float As[TILE * 128];
    __shared__ float red[4][128];
    __shared__ float dred[4][4];
    const int t = threadIdx.x;
    const int row0 = blockIdx.x * TILE;
    const int M = NP;
    #pragma unroll
    for (int i = 0; i < 4; ++i) {
        int f4 = t + i * 256;
        int r = f4 >> 5, c4 = f4 & 31;
        int gr = row0 + r;
        float4 v = make_float4(0.f, 0.f, 0.f, 0.f);
        if (gr < M) v = reinterpret_cast<const float4*>(J.A)[(size_t)gr * 32 + c4];
        reinterpret_cast<float4*>(As)[f4] = v;
    }
    __syncthreads();
    const int cg = t & 63;
    const int rg = t >> 6;
    float acc0[8], acc1[8];
    #pragma unroll
    for (int r = 0; r < 8; ++r) { acc0[r] = 0.f; acc1[r] = 0.f; }
    const float* Asr = &As[rg * 8 * 128];
    const float* W = J.W;
    for (int k = 0; k < 128; k += 4) {
        float w00 = W[(k+0)*128 + cg],    w01 = W[(k+1)*128 + cg],
              w02 = W[(k+2)*128 + cg],    w03 = W[(k+3)*128 + cg];
        float w10 = W[(k+0)*128 + cg+64], w11 = W[(k+1)*128 + cg+64],
              w12 = W[(k+2)*128 + cg+64], w13 = W[(k+3)*128 + cg+64];
        #pragma unroll
        for (int r = 0; r < 8; ++r) {
            float4 f = *reinterpret_cast<const float4*>(&Asr[r * 128 + k]);
            acc0[r] += f.x*w00 + f.y*w01 + f.z*w02 + f.w*w03;
            acc1[r] += f.x*w10 + f.y*w11 + f.z*w12 + f.w*w13;
        }
    }
    float b0 = J.bias[cg], b1 = J.bias[cg + 64];
    #pragma unroll
    for (int r = 0; r < 8; ++r) { acc0[r] += b0; acc1[r] += b1; }

    if (J.mode != 2) {
        #pragma unroll
        for (int r = 0; r < 8; ++r) {
            int gr = row0 + rg * 8 + r;
            if (gr < M) {
                J.C[(size_t)gr * 128 + cg]      = acc0[r];
                J.C[(size_t)gr * 128 + cg + 64] = acc1[r];
            }
        }
        float a10 = J.a1[cg], a11 = J.a1[cg + 64];
        float a20 = J.a2[cg], a21 = J.a2[cg + 64];
        #pragma unroll
        for (int r = 0; r < 8; ++r) {
            int node = row0 + rg * 8 + r;
            if (node >= M) break;      // wave-uniform
            float t10 = acc0[r] * a10, t11 = acc1[r] * a11;
            float t20 = acc0[r] * a20, t21 = acc1[r] * a21;
            #pragma unroll
            for (int off = 16; off; off >>= 1) {
                t10 += __shfl_xor(t10, off, 32);
                t11 += __shfl_xor(t11, off, 32);
                t20 += __shfl_xor(t20, off, 32);
                t21 += __shfl_xor(t21, off, 32);
            }
            if (cg == 0)  { J.o1[node*4+0] = t10; J.o1[node*4+2] = t11;
                            J.o2[node*4+0] = t20; J.o2[node*4+2] = t21; }
            if (cg == 32) { J.o1[node*4+1] = t10; J.o1[node*4+3] = t11;
                            J.o2[node*4+1] = t20; J.o2[node*4+3] = t21; }
        }
    } else {
        float av0 = J.a1[cg], av1 = J.a1[cg + 64];
        float e0 = J.a2[cg >> 5];
        float e1 = J.a2[2 + (cg >> 5)];
        float sacc0 = 0.f, sacc1 = 0.f, ds0 = 0.f, ds1 = 0.f;
        #pragma unroll
        for (int r = 0; r < 8; ++r) {
            int node = row0 + rg * 8 + r;
            if (node >= M) break;       // wave-uniform
            float f0 = acc0[r], f1 = acc1[r];
            float t0 = f0 * av0, t1 = f1 * av1;
            #pragma unroll
            for (int off = 16; off; off >>= 1) {
                t0 += __shfl_xor(t0, off, 32);
                t1 += __shfl_xor(t1, off, 32);
            }
            float w0 = __expf(lrelu(t0 + e0));
            float w1 = __expf(lrelu(t1 + e1));
            sacc0 += w0 * f0; sacc1 += w1 * f1;
            ds0 += w0; ds1 += w1;
        }
        red[rg][cg] = sacc0;
        red[rg][cg + 64] = sacc1;
        if (cg == 0)  { dred[rg][0] = ds0; dred[rg][2] = ds1; }
        if (cg == 32) { dred[rg][1] = ds0; dred[rg][3] = ds1; }
        __syncthreads();
        if (t < 128) {
            float s = red[0][t] + red[1][t] + red[2][t] + red[3][t];
            atomicAdd(&J.o1[t], s);
        }
        if (t < 4) {
            float s = dred[0][t] + dred[1][t] + dred[2][t] + dred[3][t];
            atomicAdd(&J.o2[t], s);
        }
    }
}

// ---------------- state linear: out[128] = feat[K] @ W[K][128] + b ----------------
__global__ void state_lin(const float* __restrict__ feat, const float* __restrict__ W,
                          const float* __restrict__ b, float* __restrict__ out, int K)
{
    int n = threadIdx.x;   // 128 threads
    float acc = b[n];
    for (int k = 0; k < K; ++k) acc += feat[k] * W[k * 128 + n];
    out[n] = acc;
}

// ---- tiny: per-head dots of Wh_in with the two state dst-attn vectors ----
__global__ void edot2(const float* __restrict__ Wh_inb, const float* __restrict__ aP,
                      const float* __restrict__ aA, float* __restrict__ edsP,
                      float* __restrict__ edsA)
{
    int t = threadIdx.x;   // 128
    int l = t & 31;
    float v = Wh_inb[t];
    float p = v * aP[t];
    float q = v * aA[t];
    #pragma unroll
    for (int off = 16; off; off >>= 1) {
        p += __shfl_xor(p, off, 32);
        q += __shfl_xor(q, off, 32);
    }
    if (l == 0) { edsP[t >> 5] = p; edsA[t >> 5] = q; }
}

// ---------------- CSR build: 4-way batched histogram / scatter ----------------
struct EdgeJobs { const int* src[4]; const int* dst[4]; int* srcsOut[4]; };

__launch_bounds__(256)
__global__ void hist4(EdgeJobs ej, int* __restrict__ counts)
{
    int y = blockIdx.y;
    int e = blockIdx.x * 256 + threadIdx.x;
    if (e < EDG) atomicAdd(&counts[y * NODE_STRIDE + ej.dst[y][e]], 1);
}

__launch_bounds__(1024)
__global__ void scan4(const int* __restrict__ counts, int* __restrict__ offsets,
                      int* __restrict__ cursor, int n)
{
    const int* cnt = counts + blockIdx.x * NODE_STRIDE;
    int* off = offsets + blockIdx.x * NODE_STRIDE;
    int* cur = cursor + blockIdx.x * NODE_STRIDE;
    int t = threadIdx.x;
    int lane = t & 63, wv = t >> 6;
    __shared__ int wsum[16];
    __shared__ int carry_s;
    if (t == 0) { carry_s = 0; off[0] = 0; }
    __syncthreads();
    for (int base = 0; base < n; base += 1024) {
        int i = base + t;
        int v = (i < n) ? cnt[i] : 0;
        int x = v;
        #pragma unroll
        for (int o = 1; o < 64; o <<= 1) {
            int y = __shfl_up(x, o, 64);
            if (lane >= o) x += y;
        }
        if (lane == 63) wsum[wv] = x;
        __syncthreads();
        if (wv == 0) {
            int y = (lane < 16) ? wsum[lane] : 0;
            #pragma unroll
            for (int o = 1; o < 16; o <<= 1) {
                int z = __shfl_up(y, o, 64);
                if (lane >= o) y += z;
            }
            if (lane < 16) wsum[lane] = y;
        }
        __syncthreads();
        int add = carry_s + (wv > 0 ? wsum[wv - 1] : 0);
        int incl = x + add;
        if (i < n) { off[i + 1] = incl; cur[i] = incl - v; }
        __syncthreads();
        if (t == 0) carry_s += wsum[15];
        __syncthreads();
    }
}

__launch_bounds__(256)
__global__ void scatter4(EdgeJobs ej, int* __restrict__ cursor)
{
    int y = blockIdx.y;
    int e = blockIdx.x * 256 + threadIdx.x;
    if (e >= EDG) return;
    int d = ej.dst[y][e];
    int pos = atomicAdd(&cursor[y * NODE_STRIDE + d], 1);
    ej.srcsOut[y][pos] = ej.src[y][e];
}

// ---- aggregate both edge types (bf16 tables); normalize, add self, relu ----
// one 64-lane wave per dst node; lane owns one dword = 2 bf16 (cols 2*lane..+1).
__launch_bounds__(256)
__global__ void aggregate2(const unsigned* __restrict__ Wh0, const int* __restrict__ off0,
                           const int* __restrict__ srcs0, const float* __restrict__ es0,
                           const float* __restrict__ ed0,
                           const unsigned* __restrict__ Wh1, const int* __restrict__ off1,
                           const int* __restrict__ srcs1, const float* __restrict__ es1,
                           const float* __restrict__ ed1,
                           float* __restrict__ out, int n)
{
    int lane = threadIdx.x & 63;
    int node = (blockIdx.x * blockDim.x + threadIdx.x) >> 6;
    if (node >= n) return;
    const int h = lane >> 4;
    float accX0 = 0.f, accY0 = 0.f, d0 = 0.f;
    float accX1 = 0.f, accY1 = 0.f, d1 = 0.f;
    {
        float edv = ed0[node * 4 + h];
        int b = off0[node], e = off0[node + 1];
        int i = b;
        for (; i + 4 <= e; i += 4) {
            int s0 = srcs0[i], s1 = srcs0[i+1], s2 = srcs0[i+2], s3 = srcs0[i+3];
            float w0 = __expf(lrelu(es0[s0*4 + h] + edv));
            float w1 = __expf(lrelu(es0[s1*4 + h] + edv));
            float w2 = __expf(lrelu(es0[s2*4 + h] + edv));
            float w3 = __expf(lrelu(es0[s3*4 + h] + edv));
            unsigned x0 = Wh0[(size_t)s0*64 + lane];
            unsigned x1 = Wh0[(size_t)s1*64 + lane];
            unsigned x2 = Wh0[(size_t)s2*64 + lane];
            unsigned x3 = Wh0[(size_t)s3*64 + lane];
            accX0 += w0*__uint_as_float(x0<<16) + w1*__uint_as_float(x1<<16)
                   + w2*__uint_as_float(x2<<16) + w3*__uint_as_float(x3<<16);
            accY0 += w0*__uint_as_float(x0&0xffff0000u) + w1*__uint_as_float(x1&0xffff0000u)
                   + w2*__uint_as_float(x2&0xffff0000u) + w3*__uint_as_float(x3&0xffff0000u);
            d0 += w0 + w1 + w2 + w3;
        }
        for (; i < e; ++i) {
            int s = srcs0[i];
            float w = __expf(lrelu(es0[s*4 + h] + edv));
            unsigned x = Wh0[(size_t)s*64 + lane];
            accX0 += w * __uint_as_float(x<<16);
            accY0 += w * __uint_as_float(x&0xffff0000u);
            d0 += w;
        }
    }
    {
        float edv = ed1[node * 4 + h];
        int b = off1[node], e = off1[node + 1];
        int i = b;
        for (; i + 4 <= e; i += 4) {
            int s0 = srcs1[i], s1 = srcs1[i+1], s2 = srcs1[i+2], s3 = srcs1[i+3];
            float w0 = __expf(lrelu(es1[s0*4 + h] + edv));
            float w1 = __expf(lrelu(es1[s1*4 + h] + edv));
            float w2 = __expf(lrelu(es1[s2*4 + h] + edv));
            float w3 = __expf(lrelu(es1[s3*4 + h] + edv));
            unsigned x0 = Wh1[(size_t)s0*64 + lane];
            unsigned x1 = Wh1[(size_t)s1*64 + lane];
            unsigned x2 = Wh1[(size_t)s2*64 + lane];
            unsigned x3 = Wh1[(size_t)s3*64 + lane];
            accX1 += w0*__uint_as_float(x0<<16) + w1*__uint_as_float(x1<<16)
                   + w2*__uint_as_float(x2<<16) + w3*__uint_as_float(x3<<16);
            accY1 += w0*__uint_as_float(x0&0xffff0000u) + w1*__uint_as_float(x1&0xffff0000u)
                   + w2*__uint_as_float(x2&0xffff0000u) + w3*__uint_as_float(x3&0xffff0000u);
            d1 += w0 + w1 + w2 + w3;
        }
        for (; i < e; ++i) {
            int s = srcs1[i];
            float w = __expf(lrelu(es1[s*4 + h] + edv));
            unsigned x = Wh1[(size_t)s*64 + lane];
            accX1 += w * __uint_as_float(x<<16);
            accY1 += w * __uint_as_float(x&0xffff0000u);
            d1 += w;
        }
    }
    float i0 = d0 > 0.f ? 1.f / d0 : 0.f;
    float i1 = d1 > 0.f ? 1.f / d1 : 0.f;
    float2* op = reinterpret_cast<float2*>(out + (size_t)node * 128) + lane;
    float2 o = *op;
    o.x += accX0 * i0 + accX1 * i1;
    o.y += accY0 * i0 + accY1 * i1;
    o.x = o.x > 0.f ? o.x : 0.f;
    o.y = o.y > 0.f ? o.y : 0.f;
    *op = o;
}

__global__ void finalize_state(const float* __restrict__ Wh_in, const float* __restrict__ SS0,
                               const float* __restrict__ dS0, const float* __restrict__ SS1,
                               const float* __restrict__ dS1, float* __restrict__ out)
{
    int t = threadIdx.x;   // 128
    int h = t >> 5;
    float v0 = dS0[h]; float i0 = v0 > 0.f ? 1.f / v0 : 0.f;
    float v1 = dS1[h]; float i1 = v1 > 0.f ? 1.f / v1 : 0.f;
    float v = Wh_in[t] + SS0[t] * i0 + SS1[t] * i1;
    out[t] = v > 0.f ? v : 0.f;
}

extern "C" void kernel_launch(void* const* d_in, const int* in_sizes, int n_in,
                              void* d_out, int out_size, void* d_ws, size_t ws_size,
                              hipStream_t stream)
{
    const float* feat_P = (const float*)d_in[0];
    const float* feat_A = (const float*)d_in[1];
    const float* feat_state = (const float*)d_in[2];
    const float* W_P   = (const float*)d_in[3];  const float* b_P   = (const float*)d_in[4];
    const float* W_A   = (const float*)d_in[5];  const float* b_A   = (const float*)d_in[6];
    const float* W_p2p = (const float*)d_in[7];  const float* b_p2p = (const float*)d_in[8];
    const float* W_p2a = (const float*)d_in[9];  const float* b_p2a = (const float*)d_in[10];
    const float* W_a2p = (const float*)d_in[11]; const float* b_a2p = (const float*)d_in[12];
    const float* W_a2a = (const float*)d_in[13]; const float* b_a2a = (const float*)d_in[14];
    const float* W_p2s = (const float*)d_in[15]; const float* b_p2s = (const float*)d_in[16];
    const float* W_a2s = (const float*)d_in[17]; const float* b_a2s = (const float*)d_in[18];
    const float* W_in  = (const float*)d_in[19]; const float* b_in  = (const float*)d_in[20];
    const float* at_p2p_s = (const float*)d_in[21]; const float* at_p2p_d = (const float*)d_in[22];
    const float* at_p2a_s = (const float*)d_in[23]; const float* at_p2a_d = (const float*)d_in[24];
    const float* at_a2p_s = (const float*)d_in[25]; const float* at_a2p_d = (const float*)d_in[26];
    const float* at_a2a_s = (const float*)d_in[27]; const float* at_a2a_d = (const float*)d_in[28];
    const float* at_p2s_s = (const float*)d_in[29]; const float* at_p2s_d = (const float*)d_in[30];
    const float* at_a2s_s = (const float*)d_in[31]; const float* at_a2s_d = (const float*)d_in[32];
    const int* src_p2p = (const int*)d_in[33]; const int* dst_p2p = (const int*)d_in[34];
    const int* src_p2a = (const int*)d_in[35]; const int* dst_p2a = (const int*)d_in[36];
    const int* src_a2p = (const int*)d_in[37]; const int* dst_a2p = (const int*)d_in[38];
    const int* src_a2a = (const int*)d_in[39]; const int* dst_a2a = (const int*)d_in[40];
    float* out = (float*)d_out;

    // ---------------- workspace layout ----------------
    char* base = (char*)d_ws;
    unsigned short* bT_p2p = (unsigned short*)base; base += (size_t)NP * HD * 2;  // 7.68 MB each
    unsigned short* bT_a2p = (unsigned short*)base; base += (size_t)NA * HD * 2;
    unsigned short* bT_p2a = (unsigned short*)base; base += (size_t)NP * HD * 2;
    unsigned short* bT_a2a = (unsigned short*)base; base += (size_t)NA * HD * 2;
    int* srcs_p2p = (int*)base;    base += (size_t)EDG * 4;
    int* srcs_a2p = (int*)base;    base += (size_t)EDG * 4;
    int* srcs_p2a = (int*)base;    base += (size_t)EDG * 4;
    int* srcs_a2a = (int*)base;    base += (size_t)EDG * 4;
    float* es_p2p = (float*)base;  base += NP * 4 * 4;
    float* es_a2p = (float*)base;  base += NA * 4 * 4;
    float* es_p2a = (float*)base;  base += NP * 4 * 4;
    float* es_a2a = (float*)base;  base += NA * 4 * 4;
    float* ed_p2p = (float*)base;  base += NP * 4 * 4;
    float* ed_a2p = (float*)base;  base += NP * 4 * 4;
    float* ed_p2a = (float*)base;  base += NA * 4 * 4;
    float* ed_a2a = (float*)base;  base += NA * 4 * 4;
    int*   counts = (int*)base;    base += 4 * NODE_STRIDE * 4;
    int*   cursor = (int*)base;    base += 4 * NODE_STRIDE * 4;
    int*   offs   = (int*)base;    base += 4 * NODE_STRIDE * 4;
    float* Wh_inb = (float*)base;  base += 128 * 4;
    float* SS0    = (float*)base;  base += 128 * 4;               // SS0,SS1,dS0,dS1 contiguous
    float* SS1    = (float*)base;  base += 128 * 4;
    float* dS0    = (float*)base;  base += 4 * 4;
    float* dS1    = (float*)base;  base += 4 * 4;
    float* edsP   = (float*)base;  base += 4 * 4;
    float* edsA   = (float*)base;  base += 4 * 4;
    size_t needed = (size_t)(base - (char*)d_ws);   // ~42 MB
    if (ws_size < needed) return;   // diagnostic guard

    int* off_p2p = offs;
    int* off_a2p = offs + NODE_STRIDE;
    int* off_p2a = offs + 2 * NODE_STRIDE;
    int* off_a2a = offs + 3 * NODE_STRIDE;

    float* outP = out;
    float* outA = out + (size_t)NP * HD;
    float* outS = out + (size_t)(NP + NA) * HD;

    const dim3 B(256);
    const int gNodeW64 = (NP * 64 + 255) / 256;   // 7500
    const int gEdgeT = (EDG + 255) / 256;         // 1563

    // ---- CSR build ----
    EdgeJobs ej;
    ej.src[0] = src_p2p; ej.dst[0] = dst_p2p; ej.srcsOut[0] = srcs_p2p;
    ej.src[1] = src_a2p; ej.dst[1] = dst_a2p; ej.srcsOut[1] = srcs_a2p;
    ej.src[2] = src_p2a; ej.dst[2] = dst_p2a; ej.srcsOut[2] = srcs_p2a;
    ej.src[3] = src_a2a; ej.dst[3] = dst_a2a; ej.srcsOut[3] = srcs_a2a;
    hipMemsetAsync(counts, 0, 4 * NODE_STRIDE * sizeof(int), stream);
    hist4<<<dim3(gEdgeT, 4), B, 0, stream>>>(ej, counts);
    scan4<<<4, 1024, 0, stream>>>(counts, offs, cursor, NP);
    scatter4<<<dim3(gEdgeT, 4), B, 0, stream>>>(ej, cursor);

    // ---- state prologue ----
    hipMemsetAsync(SS0, 0, (128 + 128 + 4 + 4) * sizeof(float), stream);
    state_lin<<<1, 128, 0, stream>>>(feat_state, W_in, b_in, Wh_inb, 64);
    edot2<<<1, 128, 0, stream>>>(Wh_inb, at_p2s_d, at_a2s_d, edsP, edsA);

    // ---- MFMA bf16: all 4 edge-type tables in one dispatch ----
    {
        MJobs m;
        m.j[0] = { feat_P, W_p2p, b_p2p, bT_p2p, at_p2p_s, es_p2p };
        m.j[1] = { feat_A, W_a2p, b_a2p, bT_a2p, at_a2p_s, es_a2p };
        m.j[2] = { feat_P, W_p2a, b_p2a, bT_p2a, at_p2a_s, es_p2a };
        m.j[3] = { feat_A, W_a2a, b_a2a, bT_a2a, at_a2a_s, es_a2a };
        gemm_mfma<<<dim3(MBPJ, 4), B, 0, stream>>>(m);
    }
    // ---- fp32: selves (mode 0, need full-precision output term) + state (mode 2) ----
    {
        GJobs g;
        g.j[0] = { feat_P, W_P,   b_P,   outP,    at_p2p_d, ed_p2p, at_a2p_d, ed_a2p, 0 };
        g.j[1] = { feat_A, W_A,   b_A,   outA,    at_p2a_d, ed_p2a, at_a2a_d, ed_a2a, 0 };
        g.j[2] = { feat_P, W_p2s, b_p2s, nullptr, at_p2s_s, SS0,    edsP,     dS0,    2 };
        g.j[3] = { feat_A, W_a2s, b_a2s, nullptr, at_a2s_s, SS1,    edsA,     dS1,    2 };
        gemm_multi<<<dim3(BPJ, 4), B, 0, stream>>>(g);
    }

    // ---- aggregates (bf16 gathers) ----
    aggregate2<<<gNodeW64, B, 0, stream>>>((const unsigned*)bT_p2p, off_p2p, srcs_p2p, es_p2p, ed_p2p,
                                           (const unsigned*)bT_a2p, off_a2p, srcs_a2p, es_a2p, ed_a2p,
                                           outP, NP);
    aggregate2<<<gNodeW64, B, 0, stream>>>((const unsigned*)bT_p2a, off_p2a, srcs_p2a, es_p2a, ed_p2a,
                                           (const unsigned*)bT_a2a, off_a2a, srcs_a2a, es_a2a, ed_a2a,
                                           outA, NA);

    finalize_state<<<1, 128, 0, stream>>>(Wh_inb, SS0, dS0, SS1, dS1, outS);
}